// Round 13
// baseline (3831.933 us; speedup 1.0000x reference)
//
#include <hip/hip_runtime.h>
#include <hip/hip_bf16.h>
#include <stdint.h>

#define BB 32
#define PP 196
#define ENC 512
#define DEC 512
#define ATTD 512
#define EE 256
#define SS 128
#define VV 10000
#define TT 127    // S-1 steps
#define NBLK 512
#define NR 2048   // gate rows

typedef unsigned short ushort_t;
typedef unsigned int uint_t;
typedef unsigned long long u64_t;
typedef float f32x4 __attribute__((ext_vector_type(4)));
typedef short s16x8 __attribute__((ext_vector_type(8)));

__device__ __forceinline__ float bf2f(ushort_t u) {
    uint_t x = ((uint_t)u) << 16;
    return __uint_as_float(x);
}
__device__ __forceinline__ float bflo(uint_t u) { return __uint_as_float(u << 16); }
__device__ __forceinline__ float bfhi(uint_t u) { return __uint_as_float(u & 0xffff0000u); }
__device__ __forceinline__ ushort_t f2bf(float f) {
    uint_t u = __float_as_uint(f);
    uint_t r = (u + 0x7FFFu + ((u >> 16) & 1u)) >> 16;
    return (ushort_t)r;
}
__device__ __forceinline__ float ftanh(float x) {
    x = fminf(15.f, fmaxf(-15.f, x));
    float e = __expf(2.f * x);
    return (e - 1.f) * __builtin_amdgcn_rcpf(e + 1.f);
}
__device__ __forceinline__ float fsig(float x) {
    return __builtin_amdgcn_rcpf(1.f + __expf(-x));
}

// ---- coherence helpers: agent-scope relaxed atomics (live at LLC) ----
__device__ __forceinline__ float aload1(const float* p) {
    return __hip_atomic_load(p, __ATOMIC_RELAXED, __HIP_MEMORY_SCOPE_AGENT);
}
__device__ __forceinline__ void astore1(float* p, float v) {
    __hip_atomic_store(p, v, __ATOMIC_RELAXED, __HIP_MEMORY_SCOPE_AGENT);
}
__device__ __forceinline__ float2 aload2(const float* p) {
    u64_t v = __hip_atomic_load((const u64_t*)p, __ATOMIC_RELAXED, __HIP_MEMORY_SCOPE_AGENT);
    float2 r;
    r.x = __uint_as_float((uint_t)v);
    r.y = __uint_as_float((uint_t)(v >> 32));
    return r;
}
__device__ __forceinline__ u64_t aload8(const ushort_t* p) {
    return __hip_atomic_load((const u64_t*)p, __ATOMIC_RELAXED, __HIP_MEMORY_SCOPE_AGENT);
}
__device__ __forceinline__ void astore_h(ushort_t* p, ushort_t v) {
    __hip_atomic_store(p, v, __ATOMIC_RELAXED, __HIP_MEMORY_SCOPE_AGENT);
}

// ---------------- prep kernels ----------------

__global__ void k_cvt(const float* __restrict__ s, ushort_t* __restrict__ d, int n) {
    for (int i = blockIdx.x * blockDim.x + threadIdx.x; i < n; i += gridDim.x * blockDim.x)
        d[i] = f2bf(s[i]);
}

// WdecT[j][k] = bf16(W_dec_att[k][j])
__global__ void k_cvtD(const float* __restrict__ Wdec, ushort_t* __restrict__ out) {
    const int n = DEC * ATTD;
    for (int i = blockIdx.x * blockDim.x + threadIdx.x; i < n; i += gridDim.x * blockDim.x) {
        int k = i & (ATTD - 1);
        int j = i >> 9;
        out[i] = f2bf(Wdec[(size_t)k * ATTD + j]);
    }
}

__global__ void k_embed_bf(const int* __restrict__ cap, const float* __restrict__ emb,
                           ushort_t* __restrict__ out) {
    const int n = TT * BB * EE;
    for (int i = blockIdx.x * blockDim.x + threadIdx.x; i < n; i += gridDim.x * blockDim.x) {
        int e = i & (EE - 1);
        int b = (i >> 8) & (BB - 1);
        int t = i >> 13;
        int tok = cap[b * SS + t];
        out[i] = f2bf(emb[(size_t)tok * EE + e]);
    }
}

// WihT_emb[k][row] = bf16(W_ih[row][k]), k < 256 (emb part)
__global__ void k_cvtT(const float* __restrict__ Wih, ushort_t* __restrict__ out) {
    const int n = EE * 4 * DEC;
    for (int i = blockIdx.x * blockDim.x + threadIdx.x; i < n; i += gridDim.x * blockDim.x) {
        int k = i & (EE - 1);
        int row = i >> 8;
        out[(size_t)k * (4 * DEC) + row] = f2bf(Wih[(size_t)row * (EE + ENC) + k]);
    }
}

// WctxT[k][row] = bf16(W_ih[row][256+k]), k < 512 (ctx part, k-major for GEMM B)
__global__ void k_cvtX(const float* __restrict__ Wih, ushort_t* __restrict__ out) {
    const int n = 512 * NR;
    for (int i = blockIdx.x * blockDim.x + threadIdx.x; i < n; i += gridDim.x * blockDim.x) {
        int row = i & (NR - 1);
        int k = i >> 11;
        out[i] = f2bf(Wih[(size_t)row * (EE + ENC) + EE + k]);
    }
}

// Whh bf16, layout [pcg][kh][kc<32][R<128][8]: row=(R&3)*512+pcg*32+(R>>2), k=kh*256+kc*8+j
__global__ void k_cvtH(const float* __restrict__ Whh, ushort_t* __restrict__ out) {
    const int n = 16 * 2 * 32 * 128 * 8;   // 1,048,576
    for (int i = blockIdx.x * blockDim.x + threadIdx.x; i < n; i += gridDim.x * blockDim.x) {
        int j = i & 7;
        int R = (i >> 3) & 127;
        int kc = (i >> 10) & 31;
        int kh = (i >> 15) & 1;
        int pcg = i >> 16;
        int row = (R & 3) * DEC + pcg * 32 + (R >> 2);
        int k = kh * 256 + kc * 8 + j;
        out[i] = f2bf(Whh[(size_t)row * DEC + k]);
    }
}

__global__ void k_bsum(const float* __restrict__ a, const float* __restrict__ b,
                       float* __restrict__ o, int n) {
    int i = blockIdx.x * blockDim.x + threadIdx.x;
    if (i < n) o[i] = a[i] + b[i];
}

__global__ void k_zerof(float* __restrict__ o, int n) {
    int i = blockIdx.x * blockDim.x + threadIdx.x;
    if (i < n) o[i] = 0.f;
}

// per-b: mean over P, then h0/c0; block 0 zeroes barrier state
__global__ __launch_bounds__(256) void k_init(const float* __restrict__ feat,
                                              const float* __restrict__ Wh, const float* __restrict__ bh,
                                              const float* __restrict__ Wc, const float* __restrict__ bc,
                                              float* __restrict__ h0, float* __restrict__ c0,
                                              int* __restrict__ bar) {
    __shared__ float ms[ENC];
    int b = blockIdx.x, t = threadIdx.x;
    if (b == 0) {
        for (int i = t; i < 4096; i += 256) bar[i] = 0;
    }
    for (int c = t; c < ENC; c += 256) {
        float s = 0.f;
        for (int p = 0; p < PP; ++p) s += feat[((size_t)b * PP + p) * ENC + c];
        ms[c] = s * (1.f / (float)PP);
    }
    __syncthreads();
    int d0 = 2 * t;
    float ah0 = 0.f, ah1 = 0.f, ac0 = 0.f, ac1 = 0.f;
    for (int k = 0; k < ENC; ++k) {
        float mk = ms[k];
        float2 wh = *(const float2*)(Wh + (size_t)k * DEC + d0);
        float2 wc = *(const float2*)(Wc + (size_t)k * DEC + d0);
        ah0 += mk * wh.x; ah1 += mk * wh.y;
        ac0 += mk * wc.x; ac1 += mk * wc.y;
    }
    h0[b * DEC + d0] = ah0 + bh[d0];
    h0[b * DEC + d0 + 1] = ah1 + bh[d0 + 1];
    c0[b * DEC + d0] = ac0 + bc[d0];
    c0[b * DEC + d0 + 1] = ac1 + bc[d0 + 1];
}

// ---------------- bf16 MFMA GEMM (128x128 tile, BK=32, 4 waves) ----------------
template <int MODE>
__global__ __launch_bounds__(256) void k_gemm(const ushort_t* __restrict__ A,
                                              const ushort_t* __restrict__ Bm,
                                              const float* __restrict__ bias,
                                              ushort_t* __restrict__ outb,
                                              float* __restrict__ outf,
                                              int M, int N, int K) {
    __shared__ __align__(16) ushort_t As[128 * 32];
    __shared__ __align__(16) ushort_t Bs[128 * 32];

    const int tid = threadIdx.x;
    const int wid = tid >> 6, lane = tid & 63;
    const int wm = wid >> 1, wn = wid & 1;
    const int lr = lane & 15, lk = (lane >> 4) * 8;
    const int row0 = blockIdx.x * 128, col0 = blockIdx.y * 128;

    f32x4 acc[4][4];
#pragma unroll
    for (int i = 0; i < 4; ++i)
#pragma unroll
        for (int j = 0; j < 4; ++j) acc[i][j] = (f32x4){0.f, 0.f, 0.f, 0.f};

    for (int k0 = 0; k0 < K; k0 += 32) {
        {
            int r = tid >> 1, kk = (tid & 1) * 16;
            int gr = row0 + r;
            uint4 v0 = {0, 0, 0, 0}, v1 = {0, 0, 0, 0};
            if (gr < M) {
                const ushort_t* sp = A + (size_t)gr * K + k0 + kk;
                v0 = *(const uint4*)sp;
                v1 = *(const uint4*)(sp + 8);
            }
            *(uint4*)(As + r * 32 + kk) = v0;
            *(uint4*)(As + r * 32 + kk + 8) = v1;
        }
        {
            int kk = tid >> 3;
            int n = (tid & 7) * 16;
            const ushort_t* sp = Bm + (size_t)(k0 + kk) * N + col0 + n;
            ushort_t tmp[16];
            if (col0 + n + 16 <= N) {
                *(uint4*)tmp = *(const uint4*)sp;
                *(uint4*)(tmp + 8) = *(const uint4*)(sp + 8);
            } else {
#pragma unroll
                for (int j = 0; j < 16; ++j) {
                    int c = col0 + n + j;
                    tmp[j] = (c < N) ? sp[j] : (ushort_t)0;
                }
            }
#pragma unroll
            for (int j = 0; j < 16; ++j) Bs[(n + j) * 32 + kk] = tmp[j];
        }
        __syncthreads();
        s16x8 af[4], bfr[4];
#pragma unroll
        for (int i = 0; i < 4; ++i)
            af[i] = *(const s16x8*)(As + (wm * 64 + i * 16 + lr) * 32 + lk);
#pragma unroll
        for (int j = 0; j < 4; ++j)
            bfr[j] = *(const s16x8*)(Bs + (wn * 64 + j * 16 + lr) * 32 + lk);
#pragma unroll
        for (int i = 0; i < 4; ++i)
#pragma unroll
            for (int j = 0; j < 4; ++j)
                acc[i][j] = __builtin_amdgcn_mfma_f32_16x16x32_bf16(af[i], bfr[j], acc[i][j], 0, 0, 0);
        __syncthreads();
    }

    const int lrow = (lane >> 4) * 4;
#pragma unroll
    for (int i = 0; i < 4; ++i) {
#pragma unroll
        for (int j = 0; j < 4; ++j) {
            int gr0 = row0 + wm * 64 + i * 16 + lrow;
            int gc = col0 + wn * 64 + j * 16 + lr;
#pragma unroll
            for (int r = 0; r < 4; ++r) {
                int gr = gr0 + r;
                if (gr < M && gc < N) {
                    float v = acc[i][j][r] + bias[gc];
                    if (MODE == 0) {
                        outb[(size_t)gr * N + gc] = f2bf(v);
                    } else {
                        int t = gr >> 5, b = gr & 31;
                        outf[((size_t)(b * TT + t)) * VV + gc] = v;
                    }
                }
            }
        }
    }
}

// ---------------- persistent recurrent kernel ----------------
// 512 blocks (2/CU). Decode: q = bid&7 (XCD heuristic), r = bid>>3;
//   pcg = 2q + (r&1);  bA = r>>1.  Group = 16 blocks sharing bA.
// 3 group-local 16-way barriers per step.
// G-linearized attention: gates_ctx = (sum_p e_p G[b,p,:]) / S with
// G = f @ Wctx^T precomputed. W_hh GEMV runs in phase B (h known);
// result crosses the barrier in one register.

__device__ __forceinline__ void gbar16(int* cnt, int target) {
    asm volatile("s_waitcnt vmcnt(0)" ::: "memory");   // drain stores to LLC
    __syncthreads();
    if (threadIdx.x == 0) {
        __hip_atomic_fetch_add(cnt, 1, __ATOMIC_RELAXED, __HIP_MEMORY_SCOPE_AGENT);
        while (__hip_atomic_load(cnt, __ATOMIC_RELAXED, __HIP_MEMORY_SCOPE_AGENT) < target)
            __builtin_amdgcn_s_sleep(1);
    }
    __syncthreads();
}

__global__ __launch_bounds__(256) void k_steps(
    const ushort_t* __restrict__ fp,
    const ushort_t* __restrict__ WdecT, const float* __restrict__ bdec,
    const float* __restrict__ vatt, const float* __restrict__ bfull,
    const ushort_t* __restrict__ Wh3, const ushort_t* __restrict__ G,
    const ushort_t* __restrict__ gemb,
    float* __restrict__ hbuf, const float* __restrict__ cbuf,
    float* __restrict__ a_glob, ushort_t* __restrict__ P, float* __restrict__ Sp,
    ushort_t* __restrict__ Hb, int* __restrict__ bar) {

    __shared__ __align__(16) float hs[8 * 68];      // h padded [kh][68]
    __shared__ __align__(16) float asS[544];        // skewed a: [ks][34]
    __shared__ __align__(16) float vsS[544];        // skewed v_att
    __shared__ float ep[16];
    __shared__ float sS[1];

    const int bid = blockIdx.x, tid = threadIdx.x;
    const float bfull_r = bfull[0];

    const int q = bid & 7, r = bid >> 3;
    const int pcg = 2 * q + (r & 1);
    const int bA = r >> 1;
    int* grpcnt = bar + 576 + bA * 32;

    // phase A: j = tid>>3 (32 j's), kh8 = tid&7 (64 k each)
    const int aj = tid >> 3, akh = tid & 7;
    const int j_abs = pcg * 32 + aj;
    const float bdec_r = bdec[j_abs];
    // phase B scores: pl = tid>>4 (0..15), ks = tid&15 (32 k each)
    const int pl = tid >> 4, ks = tid & 15;
    const int cnt_b = (pcg < 4) ? 13 : 12;
    const int p0 = (pcg < 4) ? pcg * 13 : 52 + (pcg - 4) * 12;
    // phase B G-accum: thread owns rows [rowc, rowc+8)
    const int rowc = tid * 8;
    // phase B/C hh + LSTM: R = tid>>1 (d_local*4+gate), ckh = tid&1
    const int R = tid >> 1, ckh = tid & 1;
    const int cd = pcg * 32 + (R >> 2);
    const int crow = (R & 3) * DEC + cd;
    const ushort_t* whp = Wh3 + ((size_t)(pcg * 2 + ckh) * 32) * 1024 + R * 8;

    float creg = ((tid & 7) == 0) ? cbuf[bA * DEC + cd] : 0.f;

    // persistent v_att, skewed [k&31][k>>5 stride 34]
    {
        int k0 = tid, k1 = tid + 256;
        vsS[(k0 & 31) + (k0 >> 5) * 34] = vatt[k0];
        vsS[(k1 & 31) + (k1 >> 5) * 34] = vatt[k1];
    }
    __syncthreads();

    float acc_hh = 0.f;   // carried B -> C

    for (int st = 0; st < TT; ++st) {
        const float* h_in = hbuf + (size_t)(st & 1) * BB * DEC;
        float* h_out = hbuf + (size_t)((st + 1) & 1) * BB * DEC;
        const size_t trow = (size_t)st * BB + bA;

        // ---------- phase A: a[bA][pcg*32..+32] = h@Wdec + bdec ----------
        {
            float2 hv = aload2(h_in + bA * DEC + 2 * tid);
            int k0 = 2 * tid;
            float* hrow = hs + (k0 >> 6) * 68 + (k0 & 63);
            hrow[0] = hv.x;
            hrow[1] = hv.y;
        }
        __syncthreads();
        {
            const ushort_t* wp = WdecT + (size_t)j_abs * 512 + akh * 64;
            const float* hp = hs + akh * 68;
            float acc = 0.f;
#pragma unroll
            for (int c = 0; c < 8; ++c) {
                uint4 wv = *(const uint4*)(wp + c * 8);
                f32x4 x0 = *(const f32x4*)(hp + c * 8);
                f32x4 x1 = *(const f32x4*)(hp + c * 8 + 4);
                acc += bflo(wv.x) * x0[0] + bfhi(wv.x) * x0[1]
                     + bflo(wv.y) * x0[2] + bfhi(wv.y) * x0[3]
                     + bflo(wv.z) * x1[0] + bfhi(wv.z) * x1[1]
                     + bflo(wv.w) * x1[2] + bfhi(wv.w) * x1[3];
            }
            acc += __shfl_xor(acc, 1);
            acc += __shfl_xor(acc, 2);
            acc += __shfl_xor(acc, 4);
            if (akh == 0) astore1(a_glob + bA * ATTD + j_abs, acc + bdec_r);
        }
        gbar16(grpcnt, 16 * (3 * st + 1));

        // ---------- phase B: scores; hh-GEMV; G-weighted gate partials ----------
        {
            float2 av = aload2(a_glob + bA * ATTD + 2 * tid);
            int k0 = 2 * tid;
            float* arow = asS + (k0 & 31) + (k0 >> 5) * 34;
            arow[0] = av.x;
            arow[1] = av.y;
        }
        __syncthreads();
        {
            float acc = 0.f;
            if (pl < cnt_b) {
                const int p = p0 + pl;
                const ushort_t* fr = fp + ((size_t)bA * PP + p) * ATTD + ks * 32;
                const float* ap = asS + ks * 34;
                const float* vp = vsS + ks * 34;
#pragma unroll
                for (int c2 = 0; c2 < 4; ++c2) {
                    uint4 fv = *(const uint4*)(fr + c2 * 8);
                    const int c = c2 * 8;
                    float2 a0 = *(const float2*)(ap + c),     a1 = *(const float2*)(ap + c + 2);
                    float2 a2 = *(const float2*)(ap + c + 4), a3 = *(const float2*)(ap + c + 6);
                    float2 v0 = *(const float2*)(vp + c),     v1 = *(const float2*)(vp + c + 2);
                    float2 v2 = *(const float2*)(vp + c + 4), v3 = *(const float2*)(vp + c + 6);
                    acc += ftanh(bflo(fv.x) + a0.x) * v0.x;
                    acc += ftanh(bfhi(fv.x) + a0.y) * v0.y;
                    acc += ftanh(bflo(fv.y) + a1.x) * v1.x;
                    acc += ftanh(bfhi(fv.y) + a1.y) * v1.y;
                    acc += ftanh(bflo(fv.z) + a2.x) * v2.x;
                    acc += ftanh(bfhi(fv.z) + a2.y) * v2.y;
                    acc += ftanh(bflo(fv.w) + a3.x) * v3.x;
                    acc += ftanh(bfhi(fv.w) + a3.y) * v3.y;
                }
            }
            acc += __shfl_xor(acc, 1);
            acc += __shfl_xor(acc, 2);
            acc += __shfl_xor(acc, 4);
            acc += __shfl_xor(acc, 8);
            if (ks == 0) ep[pl] = (pl < cnt_b) ? __expf(acc + bfull_r) : 0.f;
        }
        __syncthreads();
        if (tid < 16) {
            float v = ep[tid];
            v += __shfl_xor(v, 1);
            v += __shfl_xor(v, 2);
            v += __shfl_xor(v, 4);
            v += __shfl_xor(v, 8);
            if (tid == 0) astore1(Sp + bA * 16 + pcg, v);
        }
        // hh-GEMV: acc_hh = Whh[crow][ckh*256 .. +256] . h  (register carry to C)
        {
            acc_hh = 0.f;
#pragma unroll 8
            for (int kc = 0; kc < 32; ++kc) {
                uint4 wv = *(const uint4*)(whp + kc * 1024);
                int k0 = ckh * 256 + kc * 8;
                const float* xp = hs + (k0 >> 6) * 68 + (k0 & 63);
                f32x4 x0 = *(const f32x4*)xp;
                f32x4 x1 = *(const f32x4*)(xp + 4);
                acc_hh += bflo(wv.x) * x0[0] + bfhi(wv.x) * x0[1]
                        + bflo(wv.y) * x0[2] + bfhi(wv.y) * x0[3]
                        + bflo(wv.z) * x1[0] + bfhi(wv.z) * x1[1]
                        + bflo(wv.w) * x1[2] + bfhi(wv.w) * x1[3];
            }
        }
        // G-weighted gate partial for rows [rowc, rowc+8): sum_p ep[p] * G[bA,p,row]
        {
            float a8[8];
#pragma unroll
            for (int i2 = 0; i2 < 8; ++i2) a8[i2] = 0.f;
            const ushort_t* gp = G + ((size_t)(bA * PP + p0)) * NR + rowc;
            for (int p2 = 0; p2 < cnt_b; ++p2) {
                float e2 = ep[p2];
                uint4 gv = *(const uint4*)(gp + (size_t)p2 * NR);
                a8[0] += e2 * bflo(gv.x); a8[1] += e2 * bfhi(gv.x);
                a8[2] += e2 * bflo(gv.y); a8[3] += e2 * bfhi(gv.y);
                a8[4] += e2 * bflo(gv.z); a8[5] += e2 * bfhi(gv.z);
                a8[6] += e2 * bflo(gv.w); a8[7] += e2 * bfhi(gv.w);
            }
            ushort_t* pp = P + ((size_t)bA * NR + rowc) * 16 + pcg;
#pragma unroll
            for (int j2 = 0; j2 < 8; ++j2) astore_h(pp + j2 * 16, f2bf(a8[j2]));
        }
        gbar16(grpcnt, 16 * (3 * st + 2));

        // ---------- phase C: sum G-partials, add hh + emb, LSTM ----------
        {
            if (tid < 16) {
                float s = aload1(Sp + bA * 16 + tid);
                s += __shfl_xor(s, 1);
                s += __shfl_xor(s, 2);
                s += __shfl_xor(s, 4);
                s += __shfl_xor(s, 8);
                if (tid == 0) sS[0] = s;
            }
            __syncthreads();
            float gn = 0.f;
            if (ckh == 0) {
                const ushort_t* pp = P + ((size_t)bA * NR + crow) * 16;
                u64_t w0 = aload8(pp);
                u64_t w1 = aload8(pp + 4);
                u64_t w2 = aload8(pp + 8);
                u64_t w3 = aload8(pp + 12);
                float s = 0.f;
#pragma unroll
                for (int j2 = 0; j2 < 4; ++j2) s += bf2f((ushort_t)(w0 >> (16 * j2)));
#pragma unroll
                for (int j2 = 0; j2 < 4; ++j2) s += bf2f((ushort_t)(w1 >> (16 * j2)));
#pragma unroll
                for (int j2 = 0; j2 < 4; ++j2) s += bf2f((ushort_t)(w2 >> (16 * j2)));
#pragma unroll
                for (int j2 = 0; j2 < 4; ++j2) s += bf2f((ushort_t)(w3 >> (16 * j2)));
                gn = s * __builtin_amdgcn_rcpf(sS[0]);
            }
            float accp = gn + acc_hh;
            float acc = accp + __shfl_xor(accp, 1);   // combine kh halves
            acc += bf2f(gemb[trow * (4 * DEC) + crow]);
            float pf = __shfl_xor(acc, 2);
            float pg = __shfl_xor(acc, 4);
            float po = __shfl_xor(acc, 6);
            if ((tid & 7) == 0) {
                float cn = fsig(pf) * creg + fsig(acc) * ftanh(pg);
                float hn = fsig(po) * ftanh(cn);
                creg = cn;
                astore1(h_out + bA * DEC + cd, hn);
                Hb[trow * DEC + cd] = f2bf(hn);
            }
        }
        gbar16(grpcnt, 16 * (3 * st + 3));
    }
}

// ---------------- launch ----------------

extern "C" void kernel_launch(void* const* d_in, const int* in_sizes, int n_in,
                              void* d_out, int out_size, void* d_ws, size_t ws_size,
                              hipStream_t stream) {
    const float* features  = (const float*)d_in[0];
    const int*   captions  = (const int*)d_in[1];
    const float* emb       = (const float*)d_in[2];
    const float* W_enc_att = (const float*)d_in[3];
    const float* b_enc_att = (const float*)d_in[4];
    const float* W_dec_att = (const float*)d_in[5];
    const float* b_dec_att = (const float*)d_in[6];
    const float* v_att     = (const float*)d_in[7];
    const float* b_full    = (const float*)d_in[8];
    const float* W_init_h  = (const float*)d_in[9];
    const float* b_init_h  = (const float*)d_in[10];
    const float* W_init_c  = (const float*)d_in[11];
    const float* b_init_c  = (const float*)d_in[12];
    const float* W_ih      = (const float*)d_in[13];
    const float* W_hh      = (const float*)d_in[14];
    const float* b_ih      = (const float*)d_in[15];
    const float* b_hh      = (const float*)d_in[16];
    const float* W_fcn     = (const float*)d_in[17];
    const float* b_fcn     = (const float*)d_in[18];
    float* out = (float*)d_out;
    char* ws = (char*)d_ws;

    size_t o = 0;
    ushort_t* Wfcn_b  = (ushort_t*)(ws + o); o += (size_t)DEC * VV * 2;          // 10.2 MB
    ushort_t* Wenc_b  = (ushort_t*)(ws + o); o += (size_t)ENC * ATTD * 2;
    ushort_t* WdecT   = (ushort_t*)(ws + o); o += (size_t)DEC * ATTD * 2;
    ushort_t* fb      = (ushort_t*)(ws + o); o += (size_t)BB * PP * ENC * 2;     // 6.4 MB
    ushort_t* fp_b    = (ushort_t*)(ws + o); o += (size_t)BB * PP * ATTD * 2;    // 6.4 MB
    ushort_t* emb_bf  = (ushort_t*)(ws + o); o += (size_t)TT * BB * EE * 2;
    ushort_t* WihT    = (ushort_t*)(ws + o); o += (size_t)EE * 4 * DEC * 2;      // 1 MB
    ushort_t* gembuf  = (ushort_t*)(ws + o); o += (size_t)TT * BB * 4 * DEC * 2; // 16.6 MB
    ushort_t* WctxT   = (ushort_t*)(ws + o); o += (size_t)512 * NR * 2;          // 2 MB
    ushort_t* Wh3     = (ushort_t*)(ws + o); o += (size_t)16 * 2 * 32 * 128 * 8 * 2; // 2 MB
    ushort_t* G       = (ushort_t*)(ws + o); o += (size_t)BB * PP * NR * 2;      // 25.7 MB
    float*    bsum    = (float*)(ws + o);    o += (size_t)4 * DEC * 4;
    float*    zb      = (float*)(ws + o);    o += (size_t)NR * 4;
    ushort_t* Hb      = (ushort_t*)(ws + o); o += (size_t)TT * BB * DEC * 2;     // 4.2 MB
    float*    hbuf    = (float*)(ws + o);    o += (size_t)2 * BB * DEC * 4;
    float*    cbuf    = (float*)(ws + o);    o += (size_t)BB * DEC * 4;
    float*    a_glob  = (float*)(ws + o);    o += (size_t)BB * ATTD * 4;
    ushort_t* P       = (ushort_t*)(ws + o); o += (size_t)BB * NR * 16 * 2;      // 2 MB
    float*    Sp      = (float*)(ws + o);    o += (size_t)BB * 16 * 4 + 64;
    int*      bar     = (int*)(ws + o);      o += 4096 * 4;

    // prep
    k_cvt<<<2048, 256, 0, stream>>>(W_fcn, Wfcn_b, DEC * VV);
    k_cvt<<<256, 256, 0, stream>>>(W_enc_att, Wenc_b, ENC * ATTD);
    k_cvtD<<<256, 256, 0, stream>>>(W_dec_att, WdecT);
    k_cvt<<<2048, 256, 0, stream>>>(features, fb, BB * PP * ENC);
    k_embed_bf<<<1024, 256, 0, stream>>>(captions, emb, emb_bf);
    k_cvtT<<<1024, 256, 0, stream>>>(W_ih, WihT);
    k_cvtX<<<1024, 256, 0, stream>>>(W_ih, WctxT);
    k_cvtH<<<1024, 256, 0, stream>>>(W_hh, Wh3);
    k_bsum<<<8, 256, 0, stream>>>(b_ih, b_hh, bsum, 4 * DEC);
    k_zerof<<<8, 256, 0, stream>>>(zb, NR);
    k_init<<<32, 256, 0, stream>>>(features, W_init_h, b_init_h, W_init_c, b_init_c,
                                   hbuf, cbuf, bar);
    // feat_proj = features @ W_enc_att + b_enc_att (bf16)
    k_gemm<0><<<dim3((BB * PP) / 128, ATTD / 128), 256, 0, stream>>>(
        fb, Wenc_b, b_enc_att, fp_b, nullptr, BB * PP, ATTD, ENC);
    // gates_emb = embeds @ W_ih[:, :256]^T + (b_ih + b_hh)  (bf16)
    k_gemm<0><<<dim3((TT * BB + 127) / 128, (4 * DEC) / 128), 256, 0, stream>>>(
        emb_bf, WihT, bsum, gembuf, nullptr, TT * BB, 4 * DEC, EE);
    // G = features(bf16) @ Wctx^T  [6272 x 2048], zero bias
    k_gemm<0><<<dim3((BB * PP) / 128, NR / 128), 256, 0, stream>>>(
        fb, WctxT, zb, G, nullptr, BB * PP, NR, ENC);

    // persistent recurrent kernel: 512 blocks, 3 group-local 16-way barriers/step
    k_steps<<<NBLK, 256, 0, stream>>>(fp_b, WdecT, b_dec_att, v_att, b_full,
                                      Wh3, G, gembuf, hbuf, cbuf,
                                      a_glob, P, Sp, Hb, bar);

    // out = H @ W_fcn + b_fcn, scattered to [b][t][v]
    k_gemm<1><<<dim3((TT * BB + 127) / 128, (VV + 127) / 128), 256, 0, stream>>>(
        Hb, Wfcn_b, b_fcn, nullptr, out, TT * BB, VV, DEC);
}

// Round 14
// 2903.367 us; speedup vs baseline: 1.3198x; 1.3198x over previous
//
#include <hip/hip_runtime.h>
#include <hip/hip_bf16.h>
#include <stdint.h>

#define BB 32
#define PP 196
#define ENC 512
#define DEC 512
#define ATTD 512
#define EE 256
#define SS 128
#define VV 10000
#define TT 127    // S-1 steps
#define NBLK 512
#define NR 2048   // gate rows

typedef unsigned short ushort_t;
typedef unsigned int uint_t;
typedef unsigned long long u64_t;
typedef float f32x4 __attribute__((ext_vector_type(4)));
typedef short s16x8 __attribute__((ext_vector_type(8)));

__device__ __forceinline__ float bf2f(ushort_t u) {
    uint_t x = ((uint_t)u) << 16;
    return __uint_as_float(x);
}
__device__ __forceinline__ float bflo(uint_t u) { return __uint_as_float(u << 16); }
__device__ __forceinline__ float bfhi(uint_t u) { return __uint_as_float(u & 0xffff0000u); }
__device__ __forceinline__ ushort_t f2bf(float f) {
    uint_t u = __float_as_uint(f);
    uint_t r = (u + 0x7FFFu + ((u >> 16) & 1u)) >> 16;
    return (ushort_t)r;
}
__device__ __forceinline__ float ftanh(float x) {
    x = fminf(15.f, fmaxf(-15.f, x));
    float e = __expf(2.f * x);
    return (e - 1.f) * __builtin_amdgcn_rcpf(e + 1.f);
}
__device__ __forceinline__ float fsig(float x) {
    return __builtin_amdgcn_rcpf(1.f + __expf(-x));
}

// ---- coherence helpers: agent-scope relaxed atomics (live at LLC) ----
__device__ __forceinline__ float aload1(const float* p) {
    return __hip_atomic_load(p, __ATOMIC_RELAXED, __HIP_MEMORY_SCOPE_AGENT);
}
__device__ __forceinline__ void astore1(float* p, float v) {
    __hip_atomic_store(p, v, __ATOMIC_RELAXED, __HIP_MEMORY_SCOPE_AGENT);
}
__device__ __forceinline__ float2 aload2(const float* p) {
    u64_t v = __hip_atomic_load((const u64_t*)p, __ATOMIC_RELAXED, __HIP_MEMORY_SCOPE_AGENT);
    float2 r;
    r.x = __uint_as_float((uint_t)v);
    r.y = __uint_as_float((uint_t)(v >> 32));
    return r;
}
__device__ __forceinline__ ushort_t aload_h(const ushort_t* p) {
    return __hip_atomic_load(p, __ATOMIC_RELAXED, __HIP_MEMORY_SCOPE_AGENT);
}
__device__ __forceinline__ void astore8(ushort_t* p, u64_t v) {
    __hip_atomic_store((u64_t*)p, v, __ATOMIC_RELAXED, __HIP_MEMORY_SCOPE_AGENT);
}

// ---------------- prep kernels ----------------

__global__ void k_cvt(const float* __restrict__ s, ushort_t* __restrict__ d, int n) {
    for (int i = blockIdx.x * blockDim.x + threadIdx.x; i < n; i += gridDim.x * blockDim.x)
        d[i] = f2bf(s[i]);
}

// WdecT[j][k] = bf16(W_dec_att[k][j])
__global__ void k_cvtD(const float* __restrict__ Wdec, ushort_t* __restrict__ out) {
    const int n = DEC * ATTD;
    for (int i = blockIdx.x * blockDim.x + threadIdx.x; i < n; i += gridDim.x * blockDim.x) {
        int k = i & (ATTD - 1);
        int j = i >> 9;
        out[i] = f2bf(Wdec[(size_t)k * ATTD + j]);
    }
}

__global__ void k_embed_bf(const int* __restrict__ cap, const float* __restrict__ emb,
                           ushort_t* __restrict__ out) {
    const int n = TT * BB * EE;
    for (int i = blockIdx.x * blockDim.x + threadIdx.x; i < n; i += gridDim.x * blockDim.x) {
        int e = i & (EE - 1);
        int b = (i >> 8) & (BB - 1);
        int t = i >> 13;
        int tok = cap[b * SS + t];
        out[i] = f2bf(emb[(size_t)tok * EE + e]);
    }
}

// WihT_emb[k][row] = bf16(W_ih[row][k]), k < 256 (emb part)
__global__ void k_cvtT(const float* __restrict__ Wih, ushort_t* __restrict__ out) {
    const int n = EE * 4 * DEC;
    for (int i = blockIdx.x * blockDim.x + threadIdx.x; i < n; i += gridDim.x * blockDim.x) {
        int k = i & (EE - 1);
        int row = i >> 8;
        out[(size_t)k * (4 * DEC) + row] = f2bf(Wih[(size_t)row * (EE + ENC) + k]);
    }
}

// WctxT[k][c'] = bf16(W_ih[row(c')][256+k]), with row(c') = (c'&3)*512 + (c'>>2)
// (d-major permuted columns so G comes out in row' = d*4+gate order)
__global__ void k_cvtX(const float* __restrict__ Wih, ushort_t* __restrict__ out) {
    const int n = 512 * NR;
    for (int i = blockIdx.x * blockDim.x + threadIdx.x; i < n; i += gridDim.x * blockDim.x) {
        int cp = i & (NR - 1);
        int k = i >> 11;
        int row = (cp & 3) * 512 + (cp >> 2);
        out[i] = f2bf(Wih[(size_t)row * (EE + ENC) + EE + k]);
    }
}

// Whh bf16, layout [pcg][kh][kc<32][R<128][8]: row=(R&3)*512+pcg*32+(R>>2), k=kh*256+kc*8+j
__global__ void k_cvtH(const float* __restrict__ Whh, ushort_t* __restrict__ out) {
    const int n = 16 * 2 * 32 * 128 * 8;   // 1,048,576
    for (int i = blockIdx.x * blockDim.x + threadIdx.x; i < n; i += gridDim.x * blockDim.x) {
        int j = i & 7;
        int R = (i >> 3) & 127;
        int kc = (i >> 10) & 31;
        int kh = (i >> 15) & 1;
        int pcg = i >> 16;
        int row = (R & 3) * DEC + pcg * 32 + (R >> 2);
        int k = kh * 256 + kc * 8 + j;
        out[i] = f2bf(Whh[(size_t)row * DEC + k]);
    }
}

__global__ void k_bsum(const float* __restrict__ a, const float* __restrict__ b,
                       float* __restrict__ o, int n) {
    int i = blockIdx.x * blockDim.x + threadIdx.x;
    if (i < n) o[i] = a[i] + b[i];
}

__global__ void k_zerof(float* __restrict__ o, int n) {
    int i = blockIdx.x * blockDim.x + threadIdx.x;
    if (i < n) o[i] = 0.f;
}

// per-b: mean over P, then h0/c0; block 0 zeroes barrier state
__global__ __launch_bounds__(256) void k_init(const float* __restrict__ feat,
                                              const float* __restrict__ Wh, const float* __restrict__ bh,
                                              const float* __restrict__ Wc, const float* __restrict__ bc,
                                              float* __restrict__ h0, float* __restrict__ c0,
                                              int* __restrict__ bar) {
    __shared__ float ms[ENC];
    int b = blockIdx.x, t = threadIdx.x;
    if (b == 0) {
        for (int i = t; i < 4096; i += 256) bar[i] = 0;
    }
    for (int c = t; c < ENC; c += 256) {
        float s = 0.f;
        for (int p = 0; p < PP; ++p) s += feat[((size_t)b * PP + p) * ENC + c];
        ms[c] = s * (1.f / (float)PP);
    }
    __syncthreads();
    int d0 = 2 * t;
    float ah0 = 0.f, ah1 = 0.f, ac0 = 0.f, ac1 = 0.f;
    for (int k = 0; k < ENC; ++k) {
        float mk = ms[k];
        float2 wh = *(const float2*)(Wh + (size_t)k * DEC + d0);
        float2 wc = *(const float2*)(Wc + (size_t)k * DEC + d0);
        ah0 += mk * wh.x; ah1 += mk * wh.y;
        ac0 += mk * wc.x; ac1 += mk * wc.y;
    }
    h0[b * DEC + d0] = ah0 + bh[d0];
    h0[b * DEC + d0 + 1] = ah1 + bh[d0 + 1];
    c0[b * DEC + d0] = ac0 + bc[d0];
    c0[b * DEC + d0 + 1] = ac1 + bc[d0 + 1];
}

// ---------------- bf16 MFMA GEMM (128x128 tile, BK=32, 4 waves) ----------------
template <int MODE>
__global__ __launch_bounds__(256) void k_gemm(const ushort_t* __restrict__ A,
                                              const ushort_t* __restrict__ Bm,
                                              const float* __restrict__ bias,
                                              ushort_t* __restrict__ outb,
                                              float* __restrict__ outf,
                                              int M, int N, int K) {
    __shared__ __align__(16) ushort_t As[128 * 32];
    __shared__ __align__(16) ushort_t Bs[128 * 32];

    const int tid = threadIdx.x;
    const int wid = tid >> 6, lane = tid & 63;
    const int wm = wid >> 1, wn = wid & 1;
    const int lr = lane & 15, lk = (lane >> 4) * 8;
    const int row0 = blockIdx.x * 128, col0 = blockIdx.y * 128;

    f32x4 acc[4][4];
#pragma unroll
    for (int i = 0; i < 4; ++i)
#pragma unroll
        for (int j = 0; j < 4; ++j) acc[i][j] = (f32x4){0.f, 0.f, 0.f, 0.f};

    for (int k0 = 0; k0 < K; k0 += 32) {
        {
            int r = tid >> 1, kk = (tid & 1) * 16;
            int gr = row0 + r;
            uint4 v0 = {0, 0, 0, 0}, v1 = {0, 0, 0, 0};
            if (gr < M) {
                const ushort_t* sp = A + (size_t)gr * K + k0 + kk;
                v0 = *(const uint4*)sp;
                v1 = *(const uint4*)(sp + 8);
            }
            *(uint4*)(As + r * 32 + kk) = v0;
            *(uint4*)(As + r * 32 + kk + 8) = v1;
        }
        {
            int kk = tid >> 3;
            int n = (tid & 7) * 16;
            const ushort_t* sp = Bm + (size_t)(k0 + kk) * N + col0 + n;
            ushort_t tmp[16];
            if (col0 + n + 16 <= N) {
                *(uint4*)tmp = *(const uint4*)sp;
                *(uint4*)(tmp + 8) = *(const uint4*)(sp + 8);
            } else {
#pragma unroll
                for (int j = 0; j < 16; ++j) {
                    int c = col0 + n + j;
                    tmp[j] = (c < N) ? sp[j] : (ushort_t)0;
                }
            }
#pragma unroll
            for (int j = 0; j < 16; ++j) Bs[(n + j) * 32 + kk] = tmp[j];
        }
        __syncthreads();
        s16x8 af[4], bfr[4];
#pragma unroll
        for (int i = 0; i < 4; ++i)
            af[i] = *(const s16x8*)(As + (wm * 64 + i * 16 + lr) * 32 + lk);
#pragma unroll
        for (int j = 0; j < 4; ++j)
            bfr[j] = *(const s16x8*)(Bs + (wn * 64 + j * 16 + lr) * 32 + lk);
#pragma unroll
        for (int i = 0; i < 4; ++i)
#pragma unroll
            for (int j = 0; j < 4; ++j)
                acc[i][j] = __builtin_amdgcn_mfma_f32_16x16x32_bf16(af[i], bfr[j], acc[i][j], 0, 0, 0);
        __syncthreads();
    }

    const int lrow = (lane >> 4) * 4;
#pragma unroll
    for (int i = 0; i < 4; ++i) {
#pragma unroll
        for (int j = 0; j < 4; ++j) {
            int gr0 = row0 + wm * 64 + i * 16 + lrow;
            int gc = col0 + wn * 64 + j * 16 + lr;
#pragma unroll
            for (int r = 0; r < 4; ++r) {
                int gr = gr0 + r;
                if (gr < M && gc < N) {
                    float v = acc[i][j][r] + bias[gc];
                    if (MODE == 0) {
                        outb[(size_t)gr * N + gc] = f2bf(v);
                    } else {
                        int t = gr >> 5, b = gr & 31;
                        outf[((size_t)(b * TT + t)) * VV + gc] = v;
                    }
                }
            }
        }
    }
}

// ---------------- persistent recurrent kernel ----------------
// 512 blocks (2/CU). Decode: q = bid&7 (XCD heuristic), r = bid>>3;
//   pcg = 2q + (r&1);  bA = r>>1.  Group = 16 blocks sharing bA.
// 3 group-local 16-way barriers/step. G-linearized attention with
// slice-major P exchange (contiguous packed stores, coalesced reads).

__device__ __forceinline__ void gbar16(int* cnt, int target) {
    asm volatile("s_waitcnt vmcnt(0)" ::: "memory");   // drain stores to LLC
    __syncthreads();
    if (threadIdx.x == 0) {
        __hip_atomic_fetch_add(cnt, 1, __ATOMIC_RELAXED, __HIP_MEMORY_SCOPE_AGENT);
        while (__hip_atomic_load(cnt, __ATOMIC_RELAXED, __HIP_MEMORY_SCOPE_AGENT) < target)
            __builtin_amdgcn_s_sleep(1);
    }
    __syncthreads();
}

__global__ __launch_bounds__(256) void k_steps(
    const ushort_t* __restrict__ fp,
    const ushort_t* __restrict__ WdecT, const float* __restrict__ bdec,
    const float* __restrict__ vatt, const float* __restrict__ bfull,
    const ushort_t* __restrict__ Wh3, const ushort_t* __restrict__ G,
    const ushort_t* __restrict__ gemb,
    float* __restrict__ hbuf, const float* __restrict__ cbuf,
    float* __restrict__ a_glob, ushort_t* __restrict__ P, float* __restrict__ Sp,
    ushort_t* __restrict__ Hb, int* __restrict__ bar) {

    __shared__ __align__(16) float hs[8 * 68];      // h padded [kh][68]
    __shared__ __align__(16) float asS[544];        // skewed a: [ks][34]
    __shared__ __align__(16) float vsS[544];        // skewed v_att
    __shared__ float ep[16];
    __shared__ float sS[1];

    const int bid = blockIdx.x, tid = threadIdx.x;
    const float bfull_r = bfull[0];

    const int q = bid & 7, r = bid >> 3;
    const int pcg = 2 * q + (r & 1);
    const int bA = r >> 1;
    int* grpcnt = bar + 576 + bA * 32;

    // phase A: j = tid>>3 (32 j's), kh8 = tid&7 (64 k each)
    const int aj = tid >> 3, akh = tid & 7;
    const int j_abs = pcg * 32 + aj;
    const float bdec_r = bdec[j_abs];
    // phase B scores: pl = tid>>4 (0..15), ks = tid&15 (32 k each)
    const int pl = tid >> 4, ks = tid & 15;
    const int cnt_b = (pcg < 4) ? 13 : 12;
    const int p0 = (pcg < 4) ? pcg * 13 : 52 + (pcg - 4) * 12;
    // phase B G-accum: thread owns rows' [rowc, rowc+8)
    const int rowc = tid * 8;
    // phase C / hh: rl = tid>>1 (0..127 = dl*4+gate), ckh = tid&1 (K half / slice half)
    const int rl = tid >> 1, ckh = tid & 1;
    const int cd = pcg * 32 + (rl >> 2);
    const int crow = (rl & 3) * DEC + cd;
    const ushort_t* whp = Wh3 + ((size_t)(pcg * 2 + ckh) * 32) * 1024 + rl * 8;

    float creg = ((tid & 7) == 0) ? cbuf[bA * DEC + cd] : 0.f;

    // persistent v_att, skewed [k&31][k>>5 stride 34]
    {
        int k0 = tid, k1 = tid + 256;
        vsS[(k0 & 31) + (k0 >> 5) * 34] = vatt[k0];
        vsS[(k1 & 31) + (k1 >> 5) * 34] = vatt[k1];
    }
    __syncthreads();

    float acc_hh = 0.f;   // carried B -> C

    for (int st = 0; st < TT; ++st) {
        const float* h_in = hbuf + (size_t)(st & 1) * BB * DEC;
        float* h_out = hbuf + (size_t)((st + 1) & 1) * BB * DEC;
        const size_t trow = (size_t)st * BB + bA;

        // ---------- phase A: a[bA][pcg*32..+32] = h@Wdec + bdec ----------
        {
            float2 hv = aload2(h_in + bA * DEC + 2 * tid);
            int k0 = 2 * tid;
            float* hrow = hs + (k0 >> 6) * 68 + (k0 & 63);
            hrow[0] = hv.x;
            hrow[1] = hv.y;
        }
        __syncthreads();
        {
            const ushort_t* wp = WdecT + (size_t)j_abs * 512 + akh * 64;
            const float* hp = hs + akh * 68;
            float acc = 0.f;
#pragma unroll
            for (int c = 0; c < 8; ++c) {
                uint4 wv = *(const uint4*)(wp + c * 8);
                f32x4 x0 = *(const f32x4*)(hp + c * 8);
                f32x4 x1 = *(const f32x4*)(hp + c * 8 + 4);
                acc += bflo(wv.x) * x0[0] + bfhi(wv.x) * x0[1]
                     + bflo(wv.y) * x0[2] + bfhi(wv.y) * x0[3]
                     + bflo(wv.z) * x1[0] + bfhi(wv.z) * x1[1]
                     + bflo(wv.w) * x1[2] + bfhi(wv.w) * x1[3];
            }
            acc += __shfl_xor(acc, 1);
            acc += __shfl_xor(acc, 2);
            acc += __shfl_xor(acc, 4);
            if (akh == 0) astore1(a_glob + bA * ATTD + j_abs, acc + bdec_r);
        }
        gbar16(grpcnt, 16 * (3 * st + 1));

        // ---------- phase B: scores; hh-GEMV; G-weighted gate partials ----------
        {
            float2 av = aload2(a_glob + bA * ATTD + 2 * tid);
            int k0 = 2 * tid;
            float* arow = asS + (k0 & 31) + (k0 >> 5) * 34;
            arow[0] = av.x;
            arow[1] = av.y;
        }
        __syncthreads();
        {
            float acc = 0.f;
            if (pl < cnt_b) {
                const int p = p0 + pl;
                const ushort_t* fr = fp + ((size_t)bA * PP + p) * ATTD + ks * 32;
                const float* ap = asS + ks * 34;
                const float* vp = vsS + ks * 34;
#pragma unroll
                for (int c2 = 0; c2 < 4; ++c2) {
                    uint4 fv = *(const uint4*)(fr + c2 * 8);
                    const int c = c2 * 8;
                    float2 a0 = *(const float2*)(ap + c),     a1 = *(const float2*)(ap + c + 2);
                    float2 a2 = *(const float2*)(ap + c + 4), a3 = *(const float2*)(ap + c + 6);
                    float2 v0 = *(const float2*)(vp + c),     v1 = *(const float2*)(vp + c + 2);
                    float2 v2 = *(const float2*)(vp + c + 4), v3 = *(const float2*)(vp + c + 6);
                    acc += ftanh(bflo(fv.x) + a0.x) * v0.x;
                    acc += ftanh(bfhi(fv.x) + a0.y) * v0.y;
                    acc += ftanh(bflo(fv.y) + a1.x) * v1.x;
                    acc += ftanh(bfhi(fv.y) + a1.y) * v1.y;
                    acc += ftanh(bflo(fv.z) + a2.x) * v2.x;
                    acc += ftanh(bfhi(fv.z) + a2.y) * v2.y;
                    acc += ftanh(bflo(fv.w) + a3.x) * v3.x;
                    acc += ftanh(bfhi(fv.w) + a3.y) * v3.y;
                }
            }
            acc += __shfl_xor(acc, 1);
            acc += __shfl_xor(acc, 2);
            acc += __shfl_xor(acc, 4);
            acc += __shfl_xor(acc, 8);
            if (ks == 0) ep[pl] = (pl < cnt_b) ? __expf(acc + bfull_r) : 0.f;
        }
        __syncthreads();
        if (tid < 16) {
            float v = ep[tid];
            v += __shfl_xor(v, 1);
            v += __shfl_xor(v, 2);
            v += __shfl_xor(v, 4);
            v += __shfl_xor(v, 8);
            if (tid == 0) astore1(Sp + bA * 16 + pcg, v);
        }
        // hh-GEMV: acc_hh = Whh[crow][ckh*256 .. +256] . h (register carry to C)
        {
            acc_hh = 0.f;
#pragma unroll 8
            for (int kc = 0; kc < 32; ++kc) {
                uint4 wv = *(const uint4*)(whp + kc * 1024);
                int k0 = ckh * 256 + kc * 8;
                const float* xp = hs + (k0 >> 6) * 68 + (k0 & 63);
                f32x4 x0 = *(const f32x4*)xp;
                f32x4 x1 = *(const f32x4*)(xp + 4);
                acc_hh += bflo(wv.x) * x0[0] + bfhi(wv.x) * x0[1]
                        + bflo(wv.y) * x0[2] + bfhi(wv.y) * x0[3]
                        + bflo(wv.z) * x1[0] + bfhi(wv.z) * x1[1]
                        + bflo(wv.w) * x1[2] + bfhi(wv.w) * x1[3];
            }
        }
        // G-weighted gate partial rows' [rowc,rowc+8): sum_p ep[p]*G[bA,p,row']
        // -> P[(bA*16+pcg)*2048 + rowc ..] as two packed u64 stores (contiguous)
        {
            float a8[8];
#pragma unroll
            for (int i2 = 0; i2 < 8; ++i2) a8[i2] = 0.f;
            const ushort_t* gp = G + ((size_t)(bA * PP + p0)) * NR + rowc;
            for (int p2 = 0; p2 < cnt_b; ++p2) {
                float e2 = ep[p2];
                uint4 gv = *(const uint4*)(gp + (size_t)p2 * NR);
                a8[0] += e2 * bflo(gv.x); a8[1] += e2 * bfhi(gv.x);
                a8[2] += e2 * bflo(gv.y); a8[3] += e2 * bfhi(gv.y);
                a8[4] += e2 * bflo(gv.z); a8[5] += e2 * bfhi(gv.z);
                a8[6] += e2 * bflo(gv.w); a8[7] += e2 * bfhi(gv.w);
            }
            u64_t w0 = (u64_t)f2bf(a8[0]) | ((u64_t)f2bf(a8[1]) << 16)
                     | ((u64_t)f2bf(a8[2]) << 32) | ((u64_t)f2bf(a8[3]) << 48);
            u64_t w1 = (u64_t)f2bf(a8[4]) | ((u64_t)f2bf(a8[5]) << 16)
                     | ((u64_t)f2bf(a8[6]) << 32) | ((u64_t)f2bf(a8[7]) << 48);
            ushort_t* pp = P + ((size_t)(bA * 16 + pcg)) * NR + rowc;
            astore8(pp, w0);
            astore8(pp + 4, w1);
        }
        gbar16(grpcnt, 16 * (3 * st + 2));

        // ---------- phase C: sum G-partials (coalesced), add hh + emb, LSTM ----------
        {
            if (tid < 16) {
                float s = aload1(Sp + bA * 16 + tid);
                s += __shfl_xor(s, 1);
                s += __shfl_xor(s, 2);
                s += __shfl_xor(s, 4);
                s += __shfl_xor(s, 8);
                if (tid == 0) sS[0] = s;
            }
            __syncthreads();
            // my row' = pcg*128 + rl; this ckh sums slices [ckh*8, ckh*8+8)
            float gnp = 0.f;
            const ushort_t* pp = P + ((size_t)(bA * 16 + ckh * 8)) * NR + pcg * 128 + rl;
#pragma unroll
            for (int sl = 0; sl < 8; ++sl)
                gnp += bf2f(aload_h(pp + (size_t)sl * NR));
            float val = gnp * __builtin_amdgcn_rcpf(sS[0]) + acc_hh;
            float acc = val + __shfl_xor(val, 1);   // combine ckh halves
            acc += bf2f(gemb[trow * (4 * DEC) + crow]);
            float pf = __shfl_xor(acc, 2);
            float pg = __shfl_xor(acc, 4);
            float po = __shfl_xor(acc, 6);
            if ((tid & 7) == 0) {
                float cn = fsig(pf) * creg + fsig(acc) * ftanh(pg);
                float hn = fsig(po) * ftanh(cn);
                creg = cn;
                astore1(h_out + bA * DEC + cd, hn);
                Hb[trow * DEC + cd] = f2bf(hn);
            }
        }
        gbar16(grpcnt, 16 * (3 * st + 3));
    }
}

// ---------------- launch ----------------

extern "C" void kernel_launch(void* const* d_in, const int* in_sizes, int n_in,
                              void* d_out, int out_size, void* d_ws, size_t ws_size,
                              hipStream_t stream) {
    const float* features  = (const float*)d_in[0];
    const int*   captions  = (const int*)d_in[1];
    const float* emb       = (const float*)d_in[2];
    const float* W_enc_att = (const float*)d_in[3];
    const float* b_enc_att = (const float*)d_in[4];
    const float* W_dec_att = (const float*)d_in[5];
    const float* b_dec_att = (const float*)d_in[6];
    const float* v_att     = (const float*)d_in[7];
    const float* b_full    = (const float*)d_in[8];
    const float* W_init_h  = (const float*)d_in[9];
    const float* b_init_h  = (const float*)d_in[10];
    const float* W_init_c  = (const float*)d_in[11];
    const float* b_init_c  = (const float*)d_in[12];
    const float* W_ih      = (const float*)d_in[13];
    const float* W_hh      = (const float*)d_in[14];
    const float* b_ih      = (const float*)d_in[15];
    const float* b_hh      = (const float*)d_in[16];
    const float* W_fcn     = (const float*)d_in[17];
    const float* b_fcn     = (const float*)d_in[18];
    float* out = (float*)d_out;
    char* ws = (char*)d_ws;

    size_t o = 0;
    ushort_t* Wfcn_b  = (ushort_t*)(ws + o); o += (size_t)DEC * VV * 2;
    ushort_t* Wenc_b  = (ushort_t*)(ws + o); o += (size_t)ENC * ATTD * 2;
    ushort_t* WdecT   = (ushort_t*)(ws + o); o += (size_t)DEC * ATTD * 2;
    ushort_t* fb      = (ushort_t*)(ws + o); o += (size_t)BB * PP * ENC * 2;
    ushort_t* fp_b    = (ushort_t*)(ws + o); o += (size_t)BB * PP * ATTD * 2;
    ushort_t* emb_bf  = (ushort_t*)(ws + o); o += (size_t)TT * BB * EE * 2;
    ushort_t* WihT    = (ushort_t*)(ws + o); o += (size_t)EE * 4 * DEC * 2;
    ushort_t* gembuf  = (ushort_t*)(ws + o); o += (size_t)TT * BB * 4 * DEC * 2;
    ushort_t* WctxT   = (ushort_t*)(ws + o); o += (size_t)512 * NR * 2;
    ushort_t* Wh3     = (ushort_t*)(ws + o); o += (size_t)16 * 2 * 32 * 128 * 8 * 2;
    ushort_t* G       = (ushort_t*)(ws + o); o += (size_t)BB * PP * NR * 2;      // 25.7 MB
    float*    bsum    = (float*)(ws + o);    o += (size_t)4 * DEC * 4;
    float*    zb      = (float*)(ws + o);    o += (size_t)NR * 4;
    ushort_t* Hb      = (ushort_t*)(ws + o); o += (size_t)TT * BB * DEC * 2;
    float*    hbuf    = (float*)(ws + o);    o += (size_t)2 * BB * DEC * 4;
    float*    cbuf    = (float*)(ws + o);    o += (size_t)BB * DEC * 4;
    float*    a_glob  = (float*)(ws + o);    o += (size_t)BB * ATTD * 4;
    ushort_t* P       = (ushort_t*)(ws + o); o += (size_t)BB * 16 * NR * 2;      // 2 MB
    float*    Sp      = (float*)(ws + o);    o += (size_t)BB * 16 * 4 + 64;
    int*      bar     = (int*)(ws + o);      o += 4096 * 4;

    // prep
    k_cvt<<<2048, 256, 0, stream>>>(W_fcn, Wfcn_b, DEC * VV);
    k_cvt<<<256, 256, 0, stream>>>(W_enc_att, Wenc_b, ENC * ATTD);
    k_cvtD<<<256, 256, 0, stream>>>(W_dec_att, WdecT);
    k_cvt<<<2048, 256, 0, stream>>>(features, fb, BB * PP * ENC);
    k_embed_bf<<<1024, 256, 0, stream>>>(captions, emb, emb_bf);
    k_cvtT<<<1024, 256, 0, stream>>>(W_ih, WihT);
    k_cvtX<<<1024, 256, 0, stream>>>(W_ih, WctxT);
    k_cvtH<<<1024, 256, 0, stream>>>(W_hh, Wh3);
    k_bsum<<<8, 256, 0, stream>>>(b_ih, b_hh, bsum, 4 * DEC);
    k_zerof<<<8, 256, 0, stream>>>(zb, NR);
    k_init<<<32, 256, 0, stream>>>(features, W_init_h, b_init_h, W_init_c, b_init_c,
                                   hbuf, cbuf, bar);
    // feat_proj = features @ W_enc_att + b_enc_att (bf16)
    k_gemm<0><<<dim3((BB * PP) / 128, ATTD / 128), 256, 0, stream>>>(
        fb, Wenc_b, b_enc_att, fp_b, nullptr, BB * PP, ATTD, ENC);
    // gates_emb = embeds @ W_ih[:, :256]^T + (b_ih + b_hh)  (bf16)
    k_gemm<0><<<dim3((TT * BB + 127) / 128, (4 * DEC) / 128), 256, 0, stream>>>(
        emb_bf, WihT, bsum, gembuf, nullptr, TT * BB, 4 * DEC, EE);
    // G = features(bf16) @ WctxT (d-major permuted cols), zero bias
    k_gemm<0><<<dim3((BB * PP) / 128, NR / 128), 256, 0, stream>>>(
        fb, WctxT, zb, G, nullptr, BB * PP, NR, ENC);

    // persistent recurrent kernel: 512 blocks, 3 group-local 16-way barriers/step
    k_steps<<<NBLK, 256, 0, stream>>>(fp_b, WdecT, b_dec_att, v_att, b_full,
                                      Wh3, G, gembuf, hbuf, cbuf,
                                      a_glob, P, Sp, Hb, bar);

    // out = H @ W_fcn + b_fcn, scattered to [b][t][v]
    k_gemm<1><<<dim3((TT * BB + 127) / 128, (VV + 127) / 128), 256, 0, stream>>>(
        Hb, Wfcn_b, b_fcn, nullptr, out, TT * BB, VV, DEC);
}

// Round 15
// 2660.846 us; speedup vs baseline: 1.4401x; 1.0911x over previous
//
#include <hip/hip_runtime.h>
#include <hip/hip_bf16.h>
#include <stdint.h>

#define BB 32
#define PP 196
#define ENC 512
#define DEC 512
#define ATTD 512
#define EE 256
#define SS 128
#define VV 10000
#define TT 127    // S-1 steps
#define NBLK 512

typedef unsigned short ushort_t;
typedef unsigned int uint_t;
typedef unsigned long long u64_t;
typedef float f32x4 __attribute__((ext_vector_type(4)));
typedef short s16x8 __attribute__((ext_vector_type(8)));

__device__ __forceinline__ float bf2f(ushort_t u) {
    uint_t x = ((uint_t)u) << 16;
    return __uint_as_float(x);
}
__device__ __forceinline__ float bflo(uint_t u) { return __uint_as_float(u << 16); }
__device__ __forceinline__ float bfhi(uint_t u) { return __uint_as_float(u & 0xffff0000u); }
__device__ __forceinline__ ushort_t f2bf(float f) {
    uint_t u = __float_as_uint(f);
    uint_t r = (u + 0x7FFFu + ((u >> 16) & 1u)) >> 16;
    return (ushort_t)r;
}
// fast tanh/sigmoid: v_exp + v_rcp (~1e-7 rel err, budget is 7.9e-4)
__device__ __forceinline__ float ftanh(float x) {
    x = fminf(15.f, fmaxf(-15.f, x));
    float e = __expf(2.f * x);
    return (e - 1.f) * __builtin_amdgcn_rcpf(e + 1.f);
}
__device__ __forceinline__ float fsig(float x) {
    return __builtin_amdgcn_rcpf(1.f + __expf(-x));
}

// ---- coherence helpers: agent-scope relaxed atomics (live at LLC) ----
__device__ __forceinline__ float aload1(const float* p) {
    return __hip_atomic_load(p, __ATOMIC_RELAXED, __HIP_MEMORY_SCOPE_AGENT);
}
__device__ __forceinline__ void astore1(float* p, float v) {
    __hip_atomic_store(p, v, __ATOMIC_RELAXED, __HIP_MEMORY_SCOPE_AGENT);
}
__device__ __forceinline__ float2 aload2(const float* p) {
    u64_t v = __hip_atomic_load((const u64_t*)p, __ATOMIC_RELAXED, __HIP_MEMORY_SCOPE_AGENT);
    float2 r;
    r.x = __uint_as_float((uint_t)v);
    r.y = __uint_as_float((uint_t)(v >> 32));
    return r;
}

// ---------------- prep kernels ----------------

__global__ void k_cvt(const float* __restrict__ s, ushort_t* __restrict__ d, int n) {
    for (int i = blockIdx.x * blockDim.x + threadIdx.x; i < n; i += gridDim.x * blockDim.x)
        d[i] = f2bf(s[i]);
}

// WdecT[j][k] = bf16(W_dec_att[k][j])
__global__ void k_cvtD(const float* __restrict__ Wdec, ushort_t* __restrict__ out) {
    const int n = DEC * ATTD;
    for (int i = blockIdx.x * blockDim.x + threadIdx.x; i < n; i += gridDim.x * blockDim.x) {
        int k = i & (ATTD - 1);
        int j = i >> 9;
        out[i] = f2bf(Wdec[(size_t)k * ATTD + j]);
    }
}

__global__ void k_embed_bf(const int* __restrict__ cap, const float* __restrict__ emb,
                           ushort_t* __restrict__ out) {
    const int n = TT * BB * EE;
    for (int i = blockIdx.x * blockDim.x + threadIdx.x; i < n; i += gridDim.x * blockDim.x) {
        int e = i & (EE - 1);
        int b = (i >> 8) & (BB - 1);
        int t = i >> 13;
        int tok = cap[b * SS + t];
        out[i] = f2bf(emb[(size_t)tok * EE + e]);
    }
}

__global__ void k_cvtT(const float* __restrict__ Wih, ushort_t* __restrict__ out) {
    const int n = EE * 4 * DEC;
    for (int i = blockIdx.x * blockDim.x + threadIdx.x; i < n; i += gridDim.x * blockDim.x) {
        int k = i & (EE - 1);
        int row = i >> 8;
        out[(size_t)k * (4 * DEC) + row] = f2bf(Wih[(size_t)row * (EE + ENC) + k]);
    }
}

// gate weights bf16, layout [pcg][kh][kc][R][8]:
// R = d_local*4 + gate encodes (d = pcg*32+d_local, crow = gate*512+d), k = kh*512 + kc*8 + j
__global__ void k_cvtG2(const float* __restrict__ Wih, const float* __restrict__ Whh,
                        ushort_t* __restrict__ out) {
    const int n = 16 * 2 * 64 * 128 * 8;   // 2,097,152
    for (int i = blockIdx.x * blockDim.x + threadIdx.x; i < n; i += gridDim.x * blockDim.x) {
        int j = i & 7;
        int R = (i >> 3) & 127;
        int kc = (i >> 10) & 63;
        int kh = (i >> 16) & 1;
        int pcg = i >> 17;
        int d = pcg * 32 + (R >> 2);
        int gate = R & 3;
        int row = gate * DEC + d;
        int k = kh * 512 + kc * 8 + j;
        float v = (k < 512) ? Wih[(size_t)row * (EE + ENC) + EE + k]
                            : Whh[(size_t)row * DEC + (k - 512)];
        out[i] = f2bf(v);
    }
}

__global__ void k_bsum(const float* __restrict__ a, const float* __restrict__ b,
                       float* __restrict__ o, int n) {
    int i = blockIdx.x * blockDim.x + threadIdx.x;
    if (i < n) o[i] = a[i] + b[i];
}

// per-b: mean over P, then h0/c0; block 0 zeroes all barrier state
__global__ __launch_bounds__(256) void k_init(const float* __restrict__ feat,
                                              const float* __restrict__ Wh, const float* __restrict__ bh,
                                              const float* __restrict__ Wc, const float* __restrict__ bc,
                                              float* __restrict__ h0, float* __restrict__ c0,
                                              int* __restrict__ bar) {
    __shared__ float ms[ENC];
    int b = blockIdx.x, t = threadIdx.x;
    if (b == 0) {
        for (int i = t; i < 4096; i += 256) bar[i] = 0;
    }
    for (int c = t; c < ENC; c += 256) {
        float s = 0.f;
        for (int p = 0; p < PP; ++p) s += feat[((size_t)b * PP + p) * ENC + c];
        ms[c] = s * (1.f / (float)PP);
    }
    __syncthreads();
    int d0 = 2 * t;
    float ah0 = 0.f, ah1 = 0.f, ac0 = 0.f, ac1 = 0.f;
    for (int k = 0; k < ENC; ++k) {
        float mk = ms[k];
        float2 wh = *(const float2*)(Wh + (size_t)k * DEC + d0);
        float2 wc = *(const float2*)(Wc + (size_t)k * DEC + d0);
        ah0 += mk * wh.x; ah1 += mk * wh.y;
        ac0 += mk * wc.x; ac1 += mk * wc.y;
    }
    h0[b * DEC + d0] = ah0 + bh[d0];
    h0[b * DEC + d0 + 1] = ah1 + bh[d0 + 1];
    c0[b * DEC + d0] = ac0 + bc[d0];
    c0[b * DEC + d0 + 1] = ac1 + bc[d0 + 1];
}

// ---------------- bf16 MFMA GEMM (128x128 tile, BK=32, 4 waves) ----------------
template <int MODE>
__global__ __launch_bounds__(256) void k_gemm(const ushort_t* __restrict__ A,
                                              const ushort_t* __restrict__ Bm,
                                              const float* __restrict__ bias,
                                              ushort_t* __restrict__ outb,
                                              float* __restrict__ outf,
                                              int M, int N, int K) {
    __shared__ __align__(16) ushort_t As[128 * 32];
    __shared__ __align__(16) ushort_t Bs[128 * 32];

    const int tid = threadIdx.x;
    const int wid = tid >> 6, lane = tid & 63;
    const int wm = wid >> 1, wn = wid & 1;
    const int lr = lane & 15, lk = (lane >> 4) * 8;
    const int row0 = blockIdx.x * 128, col0 = blockIdx.y * 128;

    f32x4 acc[4][4];
#pragma unroll
    for (int i = 0; i < 4; ++i)
#pragma unroll
        for (int j = 0; j < 4; ++j) acc[i][j] = (f32x4){0.f, 0.f, 0.f, 0.f};

    for (int k0 = 0; k0 < K; k0 += 32) {
        {
            int r = tid >> 1, kk = (tid & 1) * 16;
            int gr = row0 + r;
            uint4 v0 = {0, 0, 0, 0}, v1 = {0, 0, 0, 0};
            if (gr < M) {
                const ushort_t* sp = A + (size_t)gr * K + k0 + kk;
                v0 = *(const uint4*)sp;
                v1 = *(const uint4*)(sp + 8);
            }
            *(uint4*)(As + r * 32 + kk) = v0;
            *(uint4*)(As + r * 32 + kk + 8) = v1;
        }
        {
            int kk = tid >> 3;
            int n = (tid & 7) * 16;
            const ushort_t* sp = Bm + (size_t)(k0 + kk) * N + col0 + n;
            ushort_t tmp[16];
            if (col0 + n + 16 <= N) {
                *(uint4*)tmp = *(const uint4*)sp;
                *(uint4*)(tmp + 8) = *(const uint4*)(sp + 8);
            } else {
#pragma unroll
                for (int j = 0; j < 16; ++j) {
                    int c = col0 + n + j;
                    tmp[j] = (c < N) ? sp[j] : (ushort_t)0;
                }
            }
#pragma unroll
            for (int j = 0; j < 16; ++j) Bs[(n + j) * 32 + kk] = tmp[j];
        }
        __syncthreads();
        s16x8 af[4], bfr[4];
#pragma unroll
        for (int i = 0; i < 4; ++i)
            af[i] = *(const s16x8*)(As + (wm * 64 + i * 16 + lr) * 32 + lk);
#pragma unroll
        for (int j = 0; j < 4; ++j)
            bfr[j] = *(const s16x8*)(Bs + (wn * 64 + j * 16 + lr) * 32 + lk);
#pragma unroll
        for (int i = 0; i < 4; ++i)
#pragma unroll
            for (int j = 0; j < 4; ++j)
                acc[i][j] = __builtin_amdgcn_mfma_f32_16x16x32_bf16(af[i], bfr[j], acc[i][j], 0, 0, 0);
        __syncthreads();
    }

    const int lrow = (lane >> 4) * 4;
#pragma unroll
    for (int i = 0; i < 4; ++i) {
#pragma unroll
        for (int j = 0; j < 4; ++j) {
            int gr0 = row0 + wm * 64 + i * 16 + lrow;
            int gc = col0 + wn * 64 + j * 16 + lr;
#pragma unroll
            for (int r = 0; r < 4; ++r) {
                int gr = gr0 + r;
                if (gr < M && gc < N) {
                    float v = acc[i][j][r] + bias[gc];
                    if (MODE == 0) {
                        outb[(size_t)gr * N + gc] = f2bf(v);
                    } else {
                        int t = gr >> 5, b = gr & 31;
                        outf[((size_t)(b * TT + t)) * VV + gc] = v;
                    }
                }
            }
        }
    }
}

// ---------------- persistent recurrent kernel ----------------
// 512 blocks (2/CU). Decode: q = bid&7 (XCD heuristic), r = bid>>3;
//   pcg = 2q + (r&1);  bA = r>>1.  Group = 16 blocks sharing bA.
// 3 group-local 16-way barriers/step. Step-invariant data (fp rows, Wdec
// slice) staged in LDS ONCE in a prologue — removes two post-barrier L2
// load trains per step.

__device__ __forceinline__ void gbar16(int* cnt, int target) {
    asm volatile("s_waitcnt vmcnt(0)" ::: "memory");   // drain stores to LLC
    __syncthreads();
    if (threadIdx.x == 0) {
        __hip_atomic_fetch_add(cnt, 1, __ATOMIC_RELAXED, __HIP_MEMORY_SCOPE_AGENT);
        while (__hip_atomic_load(cnt, __ATOMIC_RELAXED, __HIP_MEMORY_SCOPE_AGENT) < target)
            __builtin_amdgcn_s_sleep(1);
    }
    __syncthreads();
}

__global__ __launch_bounds__(256) void k_steps(
    const ushort_t* __restrict__ fp, const ushort_t* __restrict__ fb,
    const ushort_t* __restrict__ WdecT, const float* __restrict__ bdec,
    const float* __restrict__ vatt, const float* __restrict__ bfull,
    const ushort_t* __restrict__ Wg2, const ushort_t* __restrict__ gemb,
    float* __restrict__ hbuf, const float* __restrict__ cbuf,
    float* __restrict__ a_glob, float* __restrict__ ctxP, float* __restrict__ Sp,
    ushort_t* __restrict__ Hb, int* __restrict__ bar) {

    __shared__ __align__(16) float hs[8 * 68];       // h padded [kh][68]
    __shared__ __align__(16) float asS[544];         // skewed a: [ks][34]
    __shared__ __align__(16) float vsS[544];         // skewed v_att
    __shared__ __align__(16) float cs[512];
    __shared__ __align__(16) float pctx[4 * 520];
    __shared__ __align__(16) ushort_t fpL[13 * 576]; // fp rows, skewed stride 36/32-chunk
    __shared__ __align__(16) ushort_t wdL[8 * 256 * 8]; // Wdec slice, lane-contiguous
    __shared__ float ep[16];
    __shared__ float sS[1];

    const int bid = blockIdx.x, tid = threadIdx.x;
    const float bfull_r = bfull[0];

    const int q = bid & 7, r = bid >> 3;
    const int pcg = 2 * q + (r & 1);
    const int bA = r >> 1;
    int* grpcnt = bar + 576 + bA * 32;

    // phase A ids: j = tid>>3 (32 j's), kh8 = tid&7 (64 k each)
    const int aj = tid >> 3, akh = tid & 7;
    const int j_abs = pcg * 32 + aj;
    const float bdec_r = bdec[j_abs];
    // phase B ids: pl = tid>>4 (0..15), ks = tid&15 (32 k each)
    const int pl = tid >> 4, ks = tid & 15;
    const int cnt_b = (pcg < 4) ? 13 : 12;
    const int p0 = (pcg < 4) ? pcg * 13 : 52 + (pcg - 4) * 12;
    const int ps = tid >> 6, cg = tid & 63;   // ctx partial
    // phase C ids: R = tid>>1 (d_local*4+gate), ckh = tid&1 (K half)
    const int R = tid >> 1, ckh = tid & 1;
    const int cd = pcg * 32 + (R >> 2);
    const int crow = (R & 3) * DEC + cd;
    const ushort_t* wgp = Wg2 + ((size_t)(pcg * 2 + ckh) * 64) * 1024 + R * 8;

    float creg = ((tid & 7) == 0) ? cbuf[bA * DEC + cd] : 0.f;

    // ---------- prologue: stage step-invariant data into LDS ----------
    // v_att skewed [k&31][k>>5 stride 34]
    {
        int k0 = tid, k1 = tid + 256;
        vsS[(k0 & 31) + (k0 >> 5) * 34] = vatt[k0];
        vsS[(k1 & 31) + (k1 >> 5) * 34] = vatt[k1];
    }
    // fp rows for this block's p-slice: fpL[p2][ (k>>5)*36 + (k&31) ]
    for (int p2 = 0; p2 < cnt_b; ++p2) {
        uint_t v = *(const uint_t*)(fp + ((size_t)bA * PP + p0 + p2) * ATTD + 2 * tid);
        int k0 = 2 * tid;
        *(uint_t*)(fpL + p2 * 576 + (k0 >> 5) * 36 + (k0 & 31)) = v;
    }
    // Wdec slice: wdL[(c*256 + tid)*8 ..] = WdecT[j_abs][akh*64 + c*8 ..]
    {
        const ushort_t* wp = WdecT + (size_t)j_abs * 512 + akh * 64;
#pragma unroll
        for (int c = 0; c < 8; ++c)
            *(uint4*)(wdL + ((size_t)c * 256 + tid) * 8) = *(const uint4*)(wp + c * 8);
    }
    __syncthreads();

    for (int st = 0; st < TT; ++st) {
        const float* h_in = hbuf + (size_t)(st & 1) * BB * DEC;
        float* h_out = hbuf + (size_t)((st + 1) & 1) * BB * DEC;
        const size_t trow = (size_t)st * BB + bA;
        // step-indexed, barrier-independent: issue early (hides under phase A/B)
        const float gembv = bf2f(gemb[trow * (4 * DEC) + crow]);

        // ---------- phase A: a[bA][pcg*32..+32] = h@Wdec + bdec ----------
        {
            float2 hv = aload2(h_in + bA * DEC + 2 * tid);
            int k0 = 2 * tid;
            float* hrow = hs + (k0 >> 6) * 68 + (k0 & 63);
            hrow[0] = hv.x;
            hrow[1] = hv.y;
        }
        __syncthreads();
        {
            const float* hp = hs + akh * 68;
            float acc = 0.f;
#pragma unroll
            for (int c = 0; c < 8; ++c) {
                uint4 wv = *(const uint4*)(wdL + (c * 256 + tid) * 8);
                f32x4 x0 = *(const f32x4*)(hp + c * 8);
                f32x4 x1 = *(const f32x4*)(hp + c * 8 + 4);
                acc += bflo(wv.x) * x0[0] + bfhi(wv.x) * x0[1]
                     + bflo(wv.y) * x0[2] + bfhi(wv.y) * x0[3]
                     + bflo(wv.z) * x1[0] + bfhi(wv.z) * x1[1]
                     + bflo(wv.w) * x1[2] + bfhi(wv.w) * x1[3];
            }
            acc += __shfl_xor(acc, 1);
            acc += __shfl_xor(acc, 2);
            acc += __shfl_xor(acc, 4);
            if (akh == 0) astore1(a_glob + bA * ATTD + j_abs, acc + bdec_r);
        }
        gbar16(grpcnt, 16 * (3 * st + 1));

        // ---------- phase B: scores (fp from LDS) -> exp -> partial ctx/S ----------
        {
            float2 av = aload2(a_glob + bA * ATTD + 2 * tid);
            int k0 = 2 * tid;
            float* arow = asS + (k0 & 31) + (k0 >> 5) * 34;
            arow[0] = av.x;
            arow[1] = av.y;
        }
        __syncthreads();
        {
            float acc = 0.f;
            if (pl < cnt_b) {
                const ushort_t* fr = fpL + pl * 576 + ks * 36;
                const float* ap = asS + ks * 34;
                const float* vp = vsS + ks * 34;
#pragma unroll
                for (int c2 = 0; c2 < 8; ++c2) {
                    uint2 fv = *(const uint2*)(fr + c2 * 4);
                    const int c = c2 * 4;
                    float2 a0 = *(const float2*)(ap + c), a1 = *(const float2*)(ap + c + 2);
                    float2 v0 = *(const float2*)(vp + c), v1 = *(const float2*)(vp + c + 2);
                    acc += ftanh(bflo(fv.x) + a0.x) * v0.x;
                    acc += ftanh(bfhi(fv.x) + a0.y) * v0.y;
                    acc += ftanh(bflo(fv.y) + a1.x) * v1.x;
                    acc += ftanh(bfhi(fv.y) + a1.y) * v1.y;
                }
            }
            acc += __shfl_xor(acc, 1);
            acc += __shfl_xor(acc, 2);
            acc += __shfl_xor(acc, 4);
            acc += __shfl_xor(acc, 8);
            if (ks == 0) ep[pl] = (pl < cnt_b) ? __expf(acc + bfull_r) : 0.f;
        }
        __syncthreads();
        if (tid < 16) {
            float v = ep[tid];
            v += __shfl_xor(v, 1);
            v += __shfl_xor(v, 2);
            v += __shfl_xor(v, 4);
            v += __shfl_xor(v, 8);
            if (tid == 0) astore1(Sp + bA * 16 + pcg, v);
        }
        {
            float a8[8];
#pragma unroll
            for (int i2 = 0; i2 < 8; ++i2) a8[i2] = 0.f;
            for (int p2 = ps; p2 < cnt_b; p2 += 4) {
                float e2 = ep[p2];
                uint4 fv = *(const uint4*)(fb + ((size_t)bA * PP + p0 + p2) * ENC + cg * 8);
                a8[0] += e2 * bflo(fv.x); a8[1] += e2 * bfhi(fv.x);
                a8[2] += e2 * bflo(fv.y); a8[3] += e2 * bfhi(fv.y);
                a8[4] += e2 * bflo(fv.z); a8[5] += e2 * bfhi(fv.z);
                a8[6] += e2 * bflo(fv.w); a8[7] += e2 * bfhi(fv.w);
            }
            float* pp = pctx + ps * 520 + cg * 8;
            *(f32x4*)pp = (f32x4){a8[0], a8[1], a8[2], a8[3]};
            *(f32x4*)(pp + 4) = (f32x4){a8[4], a8[5], a8[6], a8[7]};
        }
        __syncthreads();
        {
            int c0i = 2 * tid, c1i = 2 * tid + 1;
            float s0 = pctx[c0i] + pctx[520 + c0i] + pctx[1040 + c0i] + pctx[1560 + c0i];
            float s1 = pctx[c1i] + pctx[520 + c1i] + pctx[1040 + c1i] + pctx[1560 + c1i];
            float* cp = ctxP + ((size_t)bA * 16 + pcg) * 512;
            astore1(cp + c0i, s0);
            astore1(cp + c1i, s1);
        }
        gbar16(grpcnt, 16 * (3 * st + 2));

        // ---------- phase C: sum partials, gate GEMV (LDS x, L2 W), LSTM ----------
        {
            if (tid < 16) {
                float s = aload1(Sp + bA * 16 + tid);
                s += __shfl_xor(s, 1);
                s += __shfl_xor(s, 2);
                s += __shfl_xor(s, 4);
                s += __shfl_xor(s, 8);
                if (tid == 0) sS[0] = s;
            }
            __syncthreads();
            const float invS = __builtin_amdgcn_rcpf(sS[0]);
            float s0 = 0.f, s1 = 0.f;
            const float* cp = ctxP + (size_t)bA * 16 * 512 + 2 * tid;
#pragma unroll
            for (int sl = 0; sl < 16; ++sl) {
                float2 v = aload2(cp + sl * 512);
                s0 += v.x;
                s1 += v.y;
            }
            cs[2 * tid] = s0 * invS;
            cs[2 * tid + 1] = s1 * invS;
        }
        __syncthreads();
        {
            float acc0 = 0.f, acc1 = 0.f;
#pragma unroll 8
            for (int kc = 0; kc < 64; ++kc) {
                uint4 wv = *(const uint4*)(wgp + kc * 1024);
                const float* xp = ckh ? (hs + (kc >> 3) * 68 + (kc & 7) * 8) : (cs + kc * 8);
                f32x4 x0 = *(const f32x4*)xp;
                f32x4 x1 = *(const f32x4*)(xp + 4);
                acc0 += bflo(wv.x) * x0[0] + bfhi(wv.x) * x0[1]
                      + bflo(wv.y) * x0[2] + bfhi(wv.y) * x0[3];
                acc1 += bflo(wv.z) * x1[0] + bfhi(wv.z) * x1[1]
                      + bflo(wv.w) * x1[2] + bfhi(wv.w) * x1[3];
            }
            float acc = acc0 + acc1;
            acc += __shfl_xor(acc, 1);       // combine K halves
            acc += gembv;
            float pf = __shfl_xor(acc, 2);
            float pg = __shfl_xor(acc, 4);
            float po = __shfl_xor(acc, 6);
            if ((tid & 7) == 0) {
                float cn = fsig(pf) * creg + fsig(acc) * ftanh(pg);
                float hn = fsig(po) * ftanh(cn);
                creg = cn;
                astore1(h_out + bA * DEC + cd, hn);
                Hb[trow * DEC + cd] = f2bf(hn);
            }
        }
        gbar16(grpcnt, 16 * (3 * st + 3));
    }
}

// ---------------- launch ----------------

extern "C" void kernel_launch(void* const* d_in, const int* in_sizes, int n_in,
                              void* d_out, int out_size, void* d_ws, size_t ws_size,
                              hipStream_t stream) {
    const float* features  = (const float*)d_in[0];
    const int*   captions  = (const int*)d_in[1];
    const float* emb       = (const float*)d_in[2];
    const float* W_enc_att = (const float*)d_in[3];
    const float* b_enc_att = (const float*)d_in[4];
    const float* W_dec_att = (const float*)d_in[5];
    const float* b_dec_att = (const float*)d_in[6];
    const float* v_att     = (const float*)d_in[7];
    const float* b_full    = (const float*)d_in[8];
    const float* W_init_h  = (const float*)d_in[9];
    const float* b_init_h  = (const float*)d_in[10];
    const float* W_init_c  = (const float*)d_in[11];
    const float* b_init_c  = (const float*)d_in[12];
    const float* W_ih      = (const float*)d_in[13];
    const float* W_hh      = (const float*)d_in[14];
    const float* b_ih      = (const float*)d_in[15];
    const float* b_hh      = (const float*)d_in[16];
    const float* W_fcn     = (const float*)d_in[17];
    const float* b_fcn     = (const float*)d_in[18];
    float* out = (float*)d_out;
    char* ws = (char*)d_ws;

    size_t o = 0;
    ushort_t* Wfcn_b  = (ushort_t*)(ws + o); o += (size_t)DEC * VV * 2;
    ushort_t* Wenc_b  = (ushort_t*)(ws + o); o += (size_t)ENC * ATTD * 2;
    ushort_t* WdecT   = (ushort_t*)(ws + o); o += (size_t)DEC * ATTD * 2;
    ushort_t* fb      = (ushort_t*)(ws + o); o += (size_t)BB * PP * ENC * 2;
    ushort_t* fp_b    = (ushort_t*)(ws + o); o += (size_t)BB * PP * ATTD * 2;
    ushort_t* emb_bf  = (ushort_t*)(ws + o); o += (size_t)TT * BB * EE * 2;
    ushort_t* WihT    = (ushort_t*)(ws + o); o += (size_t)EE * 4 * DEC * 2;
    ushort_t* gembuf  = (ushort_t*)(ws + o); o += (size_t)TT * BB * 4 * DEC * 2;
    ushort_t* Wg2     = (ushort_t*)(ws + o); o += (size_t)4 * DEC * 1024 * 2;  // 4 MB
    float*    bsum    = (float*)(ws + o);    o += (size_t)4 * DEC * 4;
    ushort_t* Hb      = (ushort_t*)(ws + o); o += (size_t)TT * BB * DEC * 2;
    float*    hbuf    = (float*)(ws + o);    o += (size_t)2 * BB * DEC * 4;
    float*    cbuf    = (float*)(ws + o);    o += (size_t)BB * DEC * 4;
    float*    a_glob  = (float*)(ws + o);    o += (size_t)BB * ATTD * 4;
    float*    ctxP    = (float*)(ws + o);    o += (size_t)BB * 16 * 512 * 4;   // 1 MB
    float*    Sp      = (float*)(ws + o);    o += (size_t)BB * 16 * 4 + 64;
    int*      bar     = (int*)(ws + o);      o += 4096 * 4;

    // prep
    k_cvt<<<2048, 256, 0, stream>>>(W_fcn, Wfcn_b, DEC * VV);
    k_cvt<<<256, 256, 0, stream>>>(W_enc_att, Wenc_b, ENC * ATTD);
    k_cvtD<<<256, 256, 0, stream>>>(W_dec_att, WdecT);
    k_cvt<<<2048, 256, 0, stream>>>(features, fb, BB * PP * ENC);
    k_embed_bf<<<1024, 256, 0, stream>>>(captions, emb, emb_bf);
    k_cvtT<<<1024, 256, 0, stream>>>(W_ih, WihT);
    k_cvtG2<<<4096, 256, 0, stream>>>(W_ih, W_hh, Wg2);
    k_bsum<<<8, 256, 0, stream>>>(b_ih, b_hh, bsum, 4 * DEC);
    k_init<<<32, 256, 0, stream>>>(features, W_init_h, b_init_h, W_init_c, b_init_c,
                                   hbuf, cbuf, bar);
    // feat_proj = features @ W_enc_att + b_enc_att (bf16)
    k_gemm<0><<<dim3((BB * PP) / 128, ATTD / 128), 256, 0, stream>>>(
        fb, Wenc_b, b_enc_att, fp_b, nullptr, BB * PP, ATTD, ENC);
    // gates_emb = embeds @ W_ih[:, :256]^T + (b_ih + b_hh)  (bf16)
    k_gemm<0><<<dim3((TT * BB + 127) / 128, (4 * DEC) / 128), 256, 0, stream>>>(
        emb_bf, WihT, bsum, gembuf, nullptr, TT * BB, 4 * DEC, EE);

    // persistent recurrent kernel: 512 blocks, 3 group-local 16-way barriers/step
    k_steps<<<NBLK, 256, 0, stream>>>(fp_b, fb, WdecT, b_dec_att, v_att, b_full,
                                      Wg2, gembuf, hbuf, cbuf,
                                      a_glob, ctxP, Sp, Hb, bar);

    // out = H @ W_fcn + b_fcn, scattered to [b][t][v]
    k_gemm<1><<<dim3((TT * BB + 127) / 128, (VV + 127) / 128), 256, 0, stream>>>(
        Hb, Wfcn_b, b_fcn, nullptr, out, TT * BB, VV, DEC);
}

// Round 16
// 2580.168 us; speedup vs baseline: 1.4851x; 1.0313x over previous
//
#include <hip/hip_runtime.h>
#include <hip/hip_bf16.h>
#include <stdint.h>

#define BB 32
#define PP 196
#define ENC 512
#define DEC 512
#define ATTD 512
#define EE 256
#define SS 128
#define VV 10000
#define TT 127    // S-1 steps
#define NBLK 512

typedef unsigned short ushort_t;
typedef unsigned int uint_t;
typedef unsigned long long u64_t;
typedef float f32x4 __attribute__((ext_vector_type(4)));
typedef short s16x8 __attribute__((ext_vector_type(8)));

__device__ __forceinline__ float bf2f(ushort_t u) {
    uint_t x = ((uint_t)u) << 16;
    return __uint_as_float(x);
}
__device__ __forceinline__ float bflo(uint_t u) { return __uint_as_float(u << 16); }
__device__ __forceinline__ float bfhi(uint_t u) { return __uint_as_float(u & 0xffff0000u); }
__device__ __forceinline__ ushort_t f2bf(float f) {
    uint_t u = __float_as_uint(f);
    uint_t r = (u + 0x7FFFu + ((u >> 16) & 1u)) >> 16;
    return (ushort_t)r;
}
// fast tanh/sigmoid: v_exp + v_rcp (~1e-7 rel err, budget is 7.9e-4)
__device__ __forceinline__ float ftanh(float x) {
    x = fminf(15.f, fmaxf(-15.f, x));
    float e = __expf(2.f * x);
    return (e - 1.f) * __builtin_amdgcn_rcpf(e + 1.f);
}
__device__ __forceinline__ float fsig(float x) {
    return __builtin_amdgcn_rcpf(1.f + __expf(-x));
}

// ---- coherence helpers: agent-scope relaxed atomics (live at LLC) ----
__device__ __forceinline__ float aload1(const float* p) {
    return __hip_atomic_load(p, __ATOMIC_RELAXED, __HIP_MEMORY_SCOPE_AGENT);
}
__device__ __forceinline__ void astore1(float* p, float v) {
    __hip_atomic_store(p, v, __ATOMIC_RELAXED, __HIP_MEMORY_SCOPE_AGENT);
}
__device__ __forceinline__ float2 aload2(const float* p) {
    u64_t v = __hip_atomic_load((const u64_t*)p, __ATOMIC_RELAXED, __HIP_MEMORY_SCOPE_AGENT);
    float2 r;
    r.x = __uint_as_float((uint_t)v);
    r.y = __uint_as_float((uint_t)(v >> 32));
    return r;
}
__device__ __forceinline__ int aload_i(const int* p) {
    return __hip_atomic_load(p, __ATOMIC_RELAXED, __HIP_MEMORY_SCOPE_AGENT);
}
__device__ __forceinline__ void astore_i(int* p, int v) {
    __hip_atomic_store(p, v, __ATOMIC_RELAXED, __HIP_MEMORY_SCOPE_AGENT);
}

// ---------------- prep kernels ----------------

__global__ void k_cvt(const float* __restrict__ s, ushort_t* __restrict__ d, int n) {
    for (int i = blockIdx.x * blockDim.x + threadIdx.x; i < n; i += gridDim.x * blockDim.x)
        d[i] = f2bf(s[i]);
}

// WdecT[j][k] = bf16(W_dec_att[k][j])
__global__ void k_cvtD(const float* __restrict__ Wdec, ushort_t* __restrict__ out) {
    const int n = DEC * ATTD;
    for (int i = blockIdx.x * blockDim.x + threadIdx.x; i < n; i += gridDim.x * blockDim.x) {
        int k = i & (ATTD - 1);
        int j = i >> 9;
        out[i] = f2bf(Wdec[(size_t)k * ATTD + j]);
    }
}

__global__ void k_embed_bf(const int* __restrict__ cap, const float* __restrict__ emb,
                           ushort_t* __restrict__ out) {
    const int n = TT * BB * EE;
    for (int i = blockIdx.x * blockDim.x + threadIdx.x; i < n; i += gridDim.x * blockDim.x) {
        int e = i & (EE - 1);
        int b = (i >> 8) & (BB - 1);
        int t = i >> 13;
        int tok = cap[b * SS + t];
        out[i] = f2bf(emb[(size_t)tok * EE + e]);
    }
}

__global__ void k_cvtT(const float* __restrict__ Wih, ushort_t* __restrict__ out) {
    const int n = EE * 4 * DEC;
    for (int i = blockIdx.x * blockDim.x + threadIdx.x; i < n; i += gridDim.x * blockDim.x) {
        int k = i & (EE - 1);
        int row = i >> 8;
        out[(size_t)k * (4 * DEC) + row] = f2bf(Wih[(size_t)row * (EE + ENC) + k]);
    }
}

// gate weights bf16, layout [pcg][kh][kc][R][8]:
// R = d_local*4 + gate encodes (d = pcg*32+d_local, crow = gate*512+d), k = kh*512 + kc*8 + j
__global__ void k_cvtG2(const float* __restrict__ Wih, const float* __restrict__ Whh,
                        ushort_t* __restrict__ out) {
    const int n = 16 * 2 * 64 * 128 * 8;   // 2,097,152
    for (int i = blockIdx.x * blockDim.x + threadIdx.x; i < n; i += gridDim.x * blockDim.x) {
        int j = i & 7;
        int R = (i >> 3) & 127;
        int kc = (i >> 10) & 63;
        int kh = (i >> 16) & 1;
        int pcg = i >> 17;
        int d = pcg * 32 + (R >> 2);
        int gate = R & 3;
        int row = gate * DEC + d;
        int k = kh * 512 + kc * 8 + j;
        float v = (k < 512) ? Wih[(size_t)row * (EE + ENC) + EE + k]
                            : Whh[(size_t)row * DEC + (k - 512)];
        out[i] = f2bf(v);
    }
}

__global__ void k_bsum(const float* __restrict__ a, const float* __restrict__ b,
                       float* __restrict__ o, int n) {
    int i = blockIdx.x * blockDim.x + threadIdx.x;
    if (i < n) o[i] = a[i] + b[i];
}

// per-b: mean over P, then h0/c0; block 0 zeroes all barrier state (64 KB)
__global__ __launch_bounds__(256) void k_init(const float* __restrict__ feat,
                                              const float* __restrict__ Wh, const float* __restrict__ bh,
                                              const float* __restrict__ Wc, const float* __restrict__ bc,
                                              float* __restrict__ h0, float* __restrict__ c0,
                                              int* __restrict__ bar) {
    __shared__ float ms[ENC];
    int b = blockIdx.x, t = threadIdx.x;
    if (b == 0) {
        for (int i = t; i < 16384; i += 256) bar[i] = 0;
    }
    for (int c = t; c < ENC; c += 256) {
        float s = 0.f;
        for (int p = 0; p < PP; ++p) s += feat[((size_t)b * PP + p) * ENC + c];
        ms[c] = s * (1.f / (float)PP);
    }
    __syncthreads();
    int d0 = 2 * t;
    float ah0 = 0.f, ah1 = 0.f, ac0 = 0.f, ac1 = 0.f;
    for (int k = 0; k < ENC; ++k) {
        float mk = ms[k];
        float2 wh = *(const float2*)(Wh + (size_t)k * DEC + d0);
        float2 wc = *(const float2*)(Wc + (size_t)k * DEC + d0);
        ah0 += mk * wh.x; ah1 += mk * wh.y;
        ac0 += mk * wc.x; ac1 += mk * wc.y;
    }
    h0[b * DEC + d0] = ah0 + bh[d0];
    h0[b * DEC + d0 + 1] = ah1 + bh[d0 + 1];
    c0[b * DEC + d0] = ac0 + bc[d0];
    c0[b * DEC + d0 + 1] = ac1 + bc[d0 + 1];
}

// ---------------- bf16 MFMA GEMM (128x128 tile, BK=32, 4 waves) ----------------
template <int MODE>
__global__ __launch_bounds__(256) void k_gemm(const ushort_t* __restrict__ A,
                                              const ushort_t* __restrict__ Bm,
                                              const float* __restrict__ bias,
                                              ushort_t* __restrict__ outb,
                                              float* __restrict__ outf,
                                              int M, int N, int K) {
    __shared__ __align__(16) ushort_t As[128 * 32];
    __shared__ __align__(16) ushort_t Bs[128 * 32];

    const int tid = threadIdx.x;
    const int wid = tid >> 6, lane = tid & 63;
    const int wm = wid >> 1, wn = wid & 1;
    const int lr = lane & 15, lk = (lane >> 4) * 8;
    const int row0 = blockIdx.x * 128, col0 = blockIdx.y * 128;

    f32x4 acc[4][4];
#pragma unroll
    for (int i = 0; i < 4; ++i)
#pragma unroll
        for (int j = 0; j < 4; ++j) acc[i][j] = (f32x4){0.f, 0.f, 0.f, 0.f};

    for (int k0 = 0; k0 < K; k0 += 32) {
        {
            int r = tid >> 1, kk = (tid & 1) * 16;
            int gr = row0 + r;
            uint4 v0 = {0, 0, 0, 0}, v1 = {0, 0, 0, 0};
            if (gr < M) {
                const ushort_t* sp = A + (size_t)gr * K + k0 + kk;
                v0 = *(const uint4*)sp;
                v1 = *(const uint4*)(sp + 8);
            }
            *(uint4*)(As + r * 32 + kk) = v0;
            *(uint4*)(As + r * 32 + kk + 8) = v1;
        }
        {
            int kk = tid >> 3;
            int n = (tid & 7) * 16;
            const ushort_t* sp = Bm + (size_t)(k0 + kk) * N + col0 + n;
            ushort_t tmp[16];
            if (col0 + n + 16 <= N) {
                *(uint4*)tmp = *(const uint4*)sp;
                *(uint4*)(tmp + 8) = *(const uint4*)(sp + 8);
            } else {
#pragma unroll
                for (int j = 0; j < 16; ++j) {
                    int c = col0 + n + j;
                    tmp[j] = (c < N) ? sp[j] : (ushort_t)0;
                }
            }
#pragma unroll
            for (int j = 0; j < 16; ++j) Bs[(n + j) * 32 + kk] = tmp[j];
        }
        __syncthreads();
        s16x8 af[4], bfr[4];
#pragma unroll
        for (int i = 0; i < 4; ++i)
            af[i] = *(const s16x8*)(As + (wm * 64 + i * 16 + lr) * 32 + lk);
#pragma unroll
        for (int j = 0; j < 4; ++j)
            bfr[j] = *(const s16x8*)(Bs + (wn * 64 + j * 16 + lr) * 32 + lk);
#pragma unroll
        for (int i = 0; i < 4; ++i)
#pragma unroll
            for (int j = 0; j < 4; ++j)
                acc[i][j] = __builtin_amdgcn_mfma_f32_16x16x32_bf16(af[i], bfr[j], acc[i][j], 0, 0, 0);
        __syncthreads();
    }

    const int lrow = (lane >> 4) * 4;
#pragma unroll
    for (int i = 0; i < 4; ++i) {
#pragma unroll
        for (int j = 0; j < 4; ++j) {
            int gr0 = row0 + wm * 64 + i * 16 + lrow;
            int gc = col0 + wn * 64 + j * 16 + lr;
#pragma unroll
            for (int r = 0; r < 4; ++r) {
                int gr = gr0 + r;
                if (gr < M && gc < N) {
                    float v = acc[i][j][r] + bias[gc];
                    if (MODE == 0) {
                        outb[(size_t)gr * N + gc] = f2bf(v);
                    } else {
                        int t = gr >> 5, b = gr & 31;
                        outf[((size_t)(b * TT + t)) * VV + gc] = v;
                    }
                }
            }
        }
    }
}

// ---------------- persistent recurrent kernel ----------------
// 512 blocks (2/CU). Decode: q = bid&7 (XCD heuristic), r = bid>>3;
//   pcg = 2q + (r&1);  bA = r>>1.  Group = 16 blocks sharing bA.
// 3 group-local 16-way FLAG barriers/step: arrival = one plain agent store
// to the block's own cacheline (no RMW serialization); wait = 16 threads
// poll the 16 flags in parallel. Monotonic targets, no reset.
// bar layout: flags[bA][slot] at bar + bA*512 + slot*32  (64 KB total)

__device__ __forceinline__ void gbar16(int* flags, int myslot, int target) {
    asm volatile("s_waitcnt vmcnt(0)" ::: "memory");   // drain data stores to LLC
    __syncthreads();
    if (threadIdx.x == 0) astore_i(flags + myslot * 32, target);
    if (threadIdx.x < 16) {
        while (aload_i(flags + (int)threadIdx.x * 32) < target)
            __builtin_amdgcn_s_sleep(1);
    }
    __syncthreads();
}

__global__ __launch_bounds__(256) void k_steps(
    const ushort_t* __restrict__ fp, const ushort_t* __restrict__ fb,
    const ushort_t* __restrict__ WdecT, const float* __restrict__ bdec,
    const float* __restrict__ vatt, const float* __restrict__ bfull,
    const ushort_t* __restrict__ Wg2, const ushort_t* __restrict__ gemb,
    float* __restrict__ hbuf, const float* __restrict__ cbuf,
    float* __restrict__ a_glob, float* __restrict__ ctxP, float* __restrict__ Sp,
    ushort_t* __restrict__ Hb, int* __restrict__ bar) {

    __shared__ __align__(16) float hs[8 * 68];       // h padded [kh][68]
    __shared__ __align__(16) float asS[544];         // skewed a: [ks][34]
    __shared__ __align__(16) float vsS[544];         // skewed v_att
    __shared__ __align__(16) float cs[512];
    __shared__ __align__(16) float pctx[4 * 520];
    __shared__ __align__(16) ushort_t fpL[13 * 576]; // fp rows, skewed stride 36/32-chunk
    __shared__ __align__(16) ushort_t wdL[8 * 256 * 8]; // Wdec slice, lane-contiguous
    __shared__ float ep[16];
    __shared__ float sS[1];

    const int bid = blockIdx.x, tid = threadIdx.x;
    const float bfull_r = bfull[0];

    const int q = bid & 7, r = bid >> 3;
    const int pcg = 2 * q + (r & 1);
    const int bA = r >> 1;
    int* flags = bar + bA * 512;

    // phase A ids: j = tid>>3 (32 j's), kh8 = tid&7 (64 k each)
    const int aj = tid >> 3, akh = tid & 7;
    const int j_abs = pcg * 32 + aj;
    const float bdec_r = bdec[j_abs];
    // phase B ids: pl = tid>>4 (0..15), ks = tid&15 (32 k each)
    const int pl = tid >> 4, ks = tid & 15;
    const int cnt_b = (pcg < 4) ? 13 : 12;
    const int p0 = (pcg < 4) ? pcg * 13 : 52 + (pcg - 4) * 12;
    const int ps = tid >> 6, cg = tid & 63;   // ctx partial
    // phase C ids: R = tid>>1 (d_local*4+gate), ckh = tid&1 (K half)
    const int R = tid >> 1, ckh = tid & 1;
    const int cd = pcg * 32 + (R >> 2);
    const int crow = (R & 3) * DEC + cd;
    const ushort_t* wgp = Wg2 + ((size_t)(pcg * 2 + ckh) * 64) * 1024 + R * 8;

    float creg = ((tid & 7) == 0) ? cbuf[bA * DEC + cd] : 0.f;

    // ---------- prologue: stage step-invariant data into LDS ----------
    {
        int k0 = tid, k1 = tid + 256;
        vsS[(k0 & 31) + (k0 >> 5) * 34] = vatt[k0];
        vsS[(k1 & 31) + (k1 >> 5) * 34] = vatt[k1];
    }
    for (int p2 = 0; p2 < cnt_b; ++p2) {
        uint_t v = *(const uint_t*)(fp + ((size_t)bA * PP + p0 + p2) * ATTD + 2 * tid);
        int k0 = 2 * tid;
        *(uint_t*)(fpL + p2 * 576 + (k0 >> 5) * 36 + (k0 & 31)) = v;
    }
    {
        const ushort_t* wp = WdecT + (size_t)j_abs * 512 + akh * 64;
#pragma unroll
        for (int c = 0; c < 8; ++c)
            *(uint4*)(wdL + ((size_t)c * 256 + tid) * 8) = *(const uint4*)(wp + c * 8);
    }
    __syncthreads();

    for (int st = 0; st < TT; ++st) {
        const float* h_in = hbuf + (size_t)(st & 1) * BB * DEC;
        float* h_out = hbuf + (size_t)((st + 1) & 1) * BB * DEC;
        const size_t trow = (size_t)st * BB + bA;
        const float gembv = bf2f(gemb[trow * (4 * DEC) + crow]);

        // ---------- phase A: a[bA][pcg*32..+32] = h@Wdec + bdec ----------
        {
            float2 hv = aload2(h_in + bA * DEC + 2 * tid);
            int k0 = 2 * tid;
            float* hrow = hs + (k0 >> 6) * 68 + (k0 & 63);
            hrow[0] = hv.x;
            hrow[1] = hv.y;
        }
        __syncthreads();
        {
            const float* hp = hs + akh * 68;
            float acc = 0.f;
#pragma unroll
            for (int c = 0; c < 8; ++c) {
                uint4 wv = *(const uint4*)(wdL + (c * 256 + tid) * 8);
                f32x4 x0 = *(const f32x4*)(hp + c * 8);
                f32x4 x1 = *(const f32x4*)(hp + c * 8 + 4);
                acc += bflo(wv.x) * x0[0] + bfhi(wv.x) * x0[1]
                     + bflo(wv.y) * x0[2] + bfhi(wv.y) * x0[3]
                     + bflo(wv.z) * x1[0] + bfhi(wv.z) * x1[1]
                     + bflo(wv.w) * x1[2] + bfhi(wv.w) * x1[3];
            }
            acc += __shfl_xor(acc, 1);
            acc += __shfl_xor(acc, 2);
            acc += __shfl_xor(acc, 4);
            if (akh == 0) astore1(a_glob + bA * ATTD + j_abs, acc + bdec_r);
        }
        gbar16(flags, pcg, 3 * st + 1);

        // ---------- phase B: scores (fp from LDS) -> exp -> partial ctx/S ----------
        {
            float2 av = aload2(a_glob + bA * ATTD + 2 * tid);
            int k0 = 2 * tid;
            float* arow = asS + (k0 & 31) + (k0 >> 5) * 34;
            arow[0] = av.x;
            arow[1] = av.y;
        }
        __syncthreads();
        {
            float acc = 0.f;
            if (pl < cnt_b) {
                const ushort_t* fr = fpL + pl * 576 + ks * 36;
                const float* ap = asS + ks * 34;
                const float* vp = vsS + ks * 34;
#pragma unroll
                for (int c2 = 0; c2 < 8; ++c2) {
                    uint2 fv = *(const uint2*)(fr + c2 * 4);
                    const int c = c2 * 4;
                    float2 a0 = *(const float2*)(ap + c), a1 = *(const float2*)(ap + c + 2);
                    float2 v0 = *(const float2*)(vp + c), v1 = *(const float2*)(vp + c + 2);
                    acc += ftanh(bflo(fv.x) + a0.x) * v0.x;
                    acc += ftanh(bfhi(fv.x) + a0.y) * v0.y;
                    acc += ftanh(bflo(fv.y) + a1.x) * v1.x;
                    acc += ftanh(bfhi(fv.y) + a1.y) * v1.y;
                }
            }
            acc += __shfl_xor(acc, 1);
            acc += __shfl_xor(acc, 2);
            acc += __shfl_xor(acc, 4);
            acc += __shfl_xor(acc, 8);
            if (ks == 0) ep[pl] = (pl < cnt_b) ? __expf(acc + bfull_r) : 0.f;
        }
        __syncthreads();
        if (tid < 16) {
            float v = ep[tid];
            v += __shfl_xor(v, 1);
            v += __shfl_xor(v, 2);
            v += __shfl_xor(v, 4);
            v += __shfl_xor(v, 8);
            if (tid == 0) astore1(Sp + bA * 16 + pcg, v);
        }
        {
            float a8[8];
#pragma unroll
            for (int i2 = 0; i2 < 8; ++i2) a8[i2] = 0.f;
            for (int p2 = ps; p2 < cnt_b; p2 += 4) {
                float e2 = ep[p2];
                uint4 fv = *(const uint4*)(fb + ((size_t)bA * PP + p0 + p2) * ENC + cg * 8);
                a8[0] += e2 * bflo(fv.x); a8[1] += e2 * bfhi(fv.x);
                a8[2] += e2 * bflo(fv.y); a8[3] += e2 * bfhi(fv.y);
                a8[4] += e2 * bflo(fv.z); a8[5] += e2 * bfhi(fv.z);
                a8[6] += e2 * bflo(fv.w); a8[7] += e2 * bfhi(fv.w);
            }
            float* pp = pctx + ps * 520 + cg * 8;
            *(f32x4*)pp = (f32x4){a8[0], a8[1], a8[2], a8[3]};
            *(f32x4*)(pp + 4) = (f32x4){a8[4], a8[5], a8[6], a8[7]};
        }
        __syncthreads();
        {
            int c0i = 2 * tid, c1i = 2 * tid + 1;
            float s0 = pctx[c0i] + pctx[520 + c0i] + pctx[1040 + c0i] + pctx[1560 + c0i];
            float s1 = pctx[c1i] + pctx[520 + c1i] + pctx[1040 + c1i] + pctx[1560 + c1i];
            float* cp = ctxP + ((size_t)bA * 16 + pcg) * 512;
            astore1(cp + c0i, s0);
            astore1(cp + c1i, s1);
        }
        gbar16(flags, pcg, 3 * st + 2);

        // ---------- phase C: sum partials, gate GEMV (LDS x, L2 W), LSTM ----------
        {
            if (tid < 16) {
                float s = aload1(Sp + bA * 16 + tid);
                s += __shfl_xor(s, 1);
                s += __shfl_xor(s, 2);
                s += __shfl_xor(s, 4);
                s += __shfl_xor(s, 8);
                if (tid == 0) sS[0] = s;
            }
            __syncthreads();
            const float invS = __builtin_amdgcn_rcpf(sS[0]);
            float s0 = 0.f, s1 = 0.f;
            const float* cp = ctxP + (size_t)bA * 16 * 512 + 2 * tid;
#pragma unroll
            for (int sl = 0; sl < 16; ++sl) {
                float2 v = aload2(cp + sl * 512);
                s0 += v.x;
                s1 += v.y;
            }
            cs[2 * tid] = s0 * invS;
            cs[2 * tid + 1] = s1 * invS;
        }
        __syncthreads();
        {
            float acc0 = 0.f, acc1 = 0.f;
#pragma unroll 8
            for (int kc = 0; kc < 64; ++kc) {
                uint4 wv = *(const uint4*)(wgp + kc * 1024);
                const float* xp = ckh ? (hs + (kc >> 3) * 68 + (kc & 7) * 8) : (cs + kc * 8);
                f32x4 x0 = *(const f32x4*)xp;
                f32x4 x1 = *(const f32x4*)(xp + 4);
                acc0 += bflo(wv.x) * x0[0] + bfhi(wv.x) * x0[1]
                      + bflo(wv.y) * x0[2] + bfhi(wv.y) * x0[3];
                acc1 += bflo(wv.z) * x1[0] + bfhi(wv.z) * x1[1]
                      + bflo(wv.w) * x1[2] + bfhi(wv.w) * x1[3];
            }
            float acc = acc0 + acc1;
            acc += __shfl_xor(acc, 1);       // combine K halves
            acc += gembv;
            float pf = __shfl_xor(acc, 2);
            float pg = __shfl_xor(acc, 4);
            float po = __shfl_xor(acc, 6);
            if ((tid & 7) == 0) {
                float cn = fsig(pf) * creg + fsig(acc) * ftanh(pg);
                float hn = fsig(po) * ftanh(cn);
                creg = cn;
                astore1(h_out + bA * DEC + cd, hn);
                Hb[trow * DEC + cd] = f2bf(hn);
            }
        }
        gbar16(flags, pcg, 3 * st + 3);
    }
}

// ---------------- launch ----------------

extern "C" void kernel_launch(void* const* d_in, const int* in_sizes, int n_in,
                              void* d_out, int out_size, void* d_ws, size_t ws_size,
                              hipStream_t stream) {
    const float* features  = (const float*)d_in[0];
    const int*   captions  = (const int*)d_in[1];
    const float* emb       = (const float*)d_in[2];
    const float* W_enc_att = (const float*)d_in[3];
    const float* b_enc_att = (const float*)d_in[4];
    const float* W_dec_att = (const float*)d_in[5];
    const float* b_dec_att = (const float*)d_in[6];
    const float* v_att     = (const float*)d_in[7];
    const float* b_full    = (const float*)d_in[8];
    const float* W_init_h  = (const float*)d_in[9];
    const float* b_init_h  = (const float*)d_in[10];
    const float* W_init_c  = (const float*)d_in[11];
    const float* b_init_c  = (const float*)d_in[12];
    const float* W_ih      = (const float*)d_in[13];
    const float* W_hh      = (const float*)d_in[14];
    const float* b_ih      = (const float*)d_in[15];
    const float* b_hh      = (const float*)d_in[16];
    const float* W_fcn     = (const float*)d_in[17];
    const float* b_fcn     = (const float*)d_in[18];
    float* out = (float*)d_out;
    char* ws = (char*)d_ws;

    size_t o = 0;
    ushort_t* Wfcn_b  = (ushort_t*)(ws + o); o += (size_t)DEC * VV * 2;
    ushort_t* Wenc_b  = (ushort_t*)(ws + o); o += (size_t)ENC * ATTD * 2;
    ushort_t* WdecT   = (ushort_t*)(ws + o); o += (size_t)DEC * ATTD * 2;
    ushort_t* fb      = (ushort_t*)(ws + o); o += (size_t)BB * PP * ENC * 2;
    ushort_t* fp_b    = (ushort_t*)(ws + o); o += (size_t)BB * PP * ATTD * 2;
    ushort_t* emb_bf  = (ushort_t*)(ws + o); o += (size_t)TT * BB * EE * 2;
    ushort_t* WihT    = (ushort_t*)(ws + o); o += (size_t)EE * 4 * DEC * 2;
    ushort_t* gembuf  = (ushort_t*)(ws + o); o += (size_t)TT * BB * 4 * DEC * 2;
    ushort_t* Wg2     = (ushort_t*)(ws + o); o += (size_t)4 * DEC * 1024 * 2;  // 4 MB
    float*    bsum    = (float*)(ws + o);    o += (size_t)4 * DEC * 4;
    ushort_t* Hb      = (ushort_t*)(ws + o); o += (size_t)TT * BB * DEC * 2;
    float*    hbuf    = (float*)(ws + o);    o += (size_t)2 * BB * DEC * 4;
    float*    cbuf    = (float*)(ws + o);    o += (size_t)BB * DEC * 4;
    float*    a_glob  = (float*)(ws + o);    o += (size_t)BB * ATTD * 4;
    float*    ctxP    = (float*)(ws + o);    o += (size_t)BB * 16 * 512 * 4;   // 1 MB
    float*    Sp      = (float*)(ws + o);    o += (size_t)BB * 16 * 4 + 64;
    int*      bar     = (int*)(ws + o);      o += 16384 * 4;   // 64 KB flag barriers

    // prep
    k_cvt<<<2048, 256, 0, stream>>>(W_fcn, Wfcn_b, DEC * VV);
    k_cvt<<<256, 256, 0, stream>>>(W_enc_att, Wenc_b, ENC * ATTD);
    k_cvtD<<<256, 256, 0, stream>>>(W_dec_att, WdecT);
    k_cvt<<<2048, 256, 0, stream>>>(features, fb, BB * PP * ENC);
    k_embed_bf<<<1024, 256, 0, stream>>>(captions, emb, emb_bf);
    k_cvtT<<<1024, 256, 0, stream>>>(W_ih, WihT);
    k_cvtG2<<<4096, 256, 0, stream>>>(W_ih, W_hh, Wg2);
    k_bsum<<<8, 256, 0, stream>>>(b_ih, b_hh, bsum, 4 * DEC);
    k_init<<<32, 256, 0, stream>>>(features, W_init_h, b_init_h, W_init_c, b_init_c,
                                   hbuf, cbuf, bar);
    // feat_proj = features @ W_enc_att + b_enc_att (bf16)
    k_gemm<0><<<dim3((BB * PP) / 128, ATTD / 128), 256, 0, stream>>>(
        fb, Wenc_b, b_enc_att, fp_b, nullptr, BB * PP, ATTD, ENC);
    // gates_emb = embeds @ W_ih[:, :256]^T + (b_ih + b_hh)  (bf16)
    k_gemm<0><<<dim3((TT * BB + 127) / 128, (4 * DEC) / 128), 256, 0, stream>>>(
        emb_bf, WihT, bsum, gembuf, nullptr, TT * BB, 4 * DEC, EE);

    // persistent recurrent kernel: 512 blocks, 3 flag barriers/step
    k_steps<<<NBLK, 256, 0, stream>>>(fp_b, fb, WdecT, b_dec_att, v_att, b_full,
                                      Wg2, gembuf, hbuf, cbuf,
                                      a_glob, ctxP, Sp, Hb, bar);

    // out = H @ W_fcn + b_fcn, scattered to [b][t][v]
    k_gemm<1><<<dim3((TT * BB + 127) / 128, (VV + 127) / 128), 256, 0, stream>>>(
        Hb, Wfcn_b, b_fcn, nullptr, out, TT * BB, VV, DEC);
}

// Round 17
// 2478.968 us; speedup vs baseline: 1.5458x; 1.0408x over previous
//
#include <hip/hip_runtime.h>
#include <hip/hip_bf16.h>
#include <stdint.h>

#define BB 32
#define PP 196
#define ENC 512
#define DEC 512
#define ATTD 512
#define EE 256
#define SS 128
#define VV 10000
#define TT 127    // S-1 steps
#define NBLK 512

typedef unsigned short ushort_t;
typedef unsigned int uint_t;
typedef unsigned long long u64_t;
typedef float f32x4 __attribute__((ext_vector_type(4)));
typedef short s16x8 __attribute__((ext_vector_type(8)));

__device__ __forceinline__ float bf2f(ushort_t u) {
    uint_t x = ((uint_t)u) << 16;
    return __uint_as_float(x);
}
__device__ __forceinline__ float bflo(uint_t u) { return __uint_as_float(u << 16); }
__device__ __forceinline__ float bfhi(uint_t u) { return __uint_as_float(u & 0xffff0000u); }
__device__ __forceinline__ ushort_t f2bf(float f) {
    uint_t u = __float_as_uint(f);
    uint_t r = (u + 0x7FFFu + ((u >> 16) & 1u)) >> 16;
    return (ushort_t)r;
}
// fast tanh/sigmoid: v_exp + v_rcp (~1e-7 rel err, budget is 7.9e-4)
__device__ __forceinline__ float ftanh(float x) {
    x = fminf(15.f, fmaxf(-15.f, x));
    float e = __expf(2.f * x);
    return (e - 1.f) * __builtin_amdgcn_rcpf(e + 1.f);
}
__device__ __forceinline__ float fsig(float x) {
    return __builtin_amdgcn_rcpf(1.f + __expf(-x));
}

// ---- coherence helpers: agent-scope relaxed atomics (live at LLC) ----
__device__ __forceinline__ float aload1(const float* p) {
    return __hip_atomic_load(p, __ATOMIC_RELAXED, __HIP_MEMORY_SCOPE_AGENT);
}
__device__ __forceinline__ void astore1(float* p, float v) {
    __hip_atomic_store(p, v, __ATOMIC_RELAXED, __HIP_MEMORY_SCOPE_AGENT);
}
__device__ __forceinline__ float2 aload2(const float* p) {
    u64_t v = __hip_atomic_load((const u64_t*)p, __ATOMIC_RELAXED, __HIP_MEMORY_SCOPE_AGENT);
    float2 r;
    r.x = __uint_as_float((uint_t)v);
    r.y = __uint_as_float((uint_t)(v >> 32));
    return r;
}
__device__ __forceinline__ int aload_i(const int* p) {
    return __hip_atomic_load(p, __ATOMIC_RELAXED, __HIP_MEMORY_SCOPE_AGENT);
}
__device__ __forceinline__ void astore_i(int* p, int v) {
    __hip_atomic_store(p, v, __ATOMIC_RELAXED, __HIP_MEMORY_SCOPE_AGENT);
}

// ---------------- prep kernels ----------------

__global__ void k_cvt(const float* __restrict__ s, ushort_t* __restrict__ d, int n) {
    for (int i = blockIdx.x * blockDim.x + threadIdx.x; i < n; i += gridDim.x * blockDim.x)
        d[i] = f2bf(s[i]);
}

// WdecT[j][k] = bf16(W_dec_att[k][j])
__global__ void k_cvtD(const float* __restrict__ Wdec, ushort_t* __restrict__ out) {
    const int n = DEC * ATTD;
    for (int i = blockIdx.x * blockDim.x + threadIdx.x; i < n; i += gridDim.x * blockDim.x) {
        int k = i & (ATTD - 1);
        int j = i >> 9;
        out[i] = f2bf(Wdec[(size_t)k * ATTD + j]);
    }
}

__global__ void k_embed_bf(const int* __restrict__ cap, const float* __restrict__ emb,
                           ushort_t* __restrict__ out) {
    const int n = TT * BB * EE;
    for (int i = blockIdx.x * blockDim.x + threadIdx.x; i < n; i += gridDim.x * blockDim.x) {
        int e = i & (EE - 1);
        int b = (i >> 8) & (BB - 1);
        int t = i >> 13;
        int tok = cap[b * SS + t];
        out[i] = f2bf(emb[(size_t)tok * EE + e]);
    }
}

__global__ void k_cvtT(const float* __restrict__ Wih, ushort_t* __restrict__ out) {
    const int n = EE * 4 * DEC;
    for (int i = blockIdx.x * blockDim.x + threadIdx.x; i < n; i += gridDim.x * blockDim.x) {
        int k = i & (EE - 1);
        int row = i >> 8;
        out[(size_t)k * (4 * DEC) + row] = f2bf(Wih[(size_t)row * (EE + ENC) + k]);
    }
}

// gate weights bf16, layout [pcg][kh][kc][R][8]:
// R = d_local*4 + gate encodes (d = pcg*32+d_local, crow = gate*512+d), k = kh*512 + kc*8 + j
__global__ void k_cvtG2(const float* __restrict__ Wih, const float* __restrict__ Whh,
                        ushort_t* __restrict__ out) {
    const int n = 16 * 2 * 64 * 128 * 8;   // 2,097,152
    for (int i = blockIdx.x * blockDim.x + threadIdx.x; i < n; i += gridDim.x * blockDim.x) {
        int j = i & 7;
        int R = (i >> 3) & 127;
        int kc = (i >> 10) & 63;
        int kh = (i >> 16) & 1;
        int pcg = i >> 17;
        int d = pcg * 32 + (R >> 2);
        int gate = R & 3;
        int row = gate * DEC + d;
        int k = kh * 512 + kc * 8 + j;
        float v = (k < 512) ? Wih[(size_t)row * (EE + ENC) + EE + k]
                            : Whh[(size_t)row * DEC + (k - 512)];
        out[i] = f2bf(v);
    }
}

__global__ void k_bsum(const float* __restrict__ a, const float* __restrict__ b,
                       float* __restrict__ o, int n) {
    int i = blockIdx.x * blockDim.x + threadIdx.x;
    if (i < n) o[i] = a[i] + b[i];
}

// per-b: mean over P, then h0/c0; block 0 zeroes all barrier state (64 KB)
__global__ __launch_bounds__(256) void k_init(const float* __restrict__ feat,
                                              const float* __restrict__ Wh, const float* __restrict__ bh,
                                              const float* __restrict__ Wc, const float* __restrict__ bc,
                                              float* __restrict__ h0, float* __restrict__ c0,
                                              int* __restrict__ bar) {
    __shared__ float ms[ENC];
    int b = blockIdx.x, t = threadIdx.x;
    if (b == 0) {
        for (int i = t; i < 16384; i += 256) bar[i] = 0;
    }
    for (int c = t; c < ENC; c += 256) {
        float s = 0.f;
        for (int p = 0; p < PP; ++p) s += feat[((size_t)b * PP + p) * ENC + c];
        ms[c] = s * (1.f / (float)PP);
    }
    __syncthreads();
    int d0 = 2 * t;
    float ah0 = 0.f, ah1 = 0.f, ac0 = 0.f, ac1 = 0.f;
    for (int k = 0; k < ENC; ++k) {
        float mk = ms[k];
        float2 wh = *(const float2*)(Wh + (size_t)k * DEC + d0);
        float2 wc = *(const float2*)(Wc + (size_t)k * DEC + d0);
        ah0 += mk * wh.x; ah1 += mk * wh.y;
        ac0 += mk * wc.x; ac1 += mk * wc.y;
    }
    h0[b * DEC + d0] = ah0 + bh[d0];
    h0[b * DEC + d0 + 1] = ah1 + bh[d0 + 1];
    c0[b * DEC + d0] = ac0 + bc[d0];
    c0[b * DEC + d0 + 1] = ac1 + bc[d0 + 1];
}

// ---------------- bf16 MFMA GEMM (128x128 tile, BK=32, 4 waves) ----------------
template <int MODE>
__global__ __launch_bounds__(256) void k_gemm(const ushort_t* __restrict__ A,
                                              const ushort_t* __restrict__ Bm,
                                              const float* __restrict__ bias,
                                              ushort_t* __restrict__ outb,
                                              float* __restrict__ outf,
                                              int M, int N, int K) {
    __shared__ __align__(16) ushort_t As[128 * 32];
    __shared__ __align__(16) ushort_t Bs[128 * 32];

    const int tid = threadIdx.x;
    const int wid = tid >> 6, lane = tid & 63;
    const int wm = wid >> 1, wn = wid & 1;
    const int lr = lane & 15, lk = (lane >> 4) * 8;
    const int row0 = blockIdx.x * 128, col0 = blockIdx.y * 128;

    f32x4 acc[4][4];
#pragma unroll
    for (int i = 0; i < 4; ++i)
#pragma unroll
        for (int j = 0; j < 4; ++j) acc[i][j] = (f32x4){0.f, 0.f, 0.f, 0.f};

    for (int k0 = 0; k0 < K; k0 += 32) {
        {
            int r = tid >> 1, kk = (tid & 1) * 16;
            int gr = row0 + r;
            uint4 v0 = {0, 0, 0, 0}, v1 = {0, 0, 0, 0};
            if (gr < M) {
                const ushort_t* sp = A + (size_t)gr * K + k0 + kk;
                v0 = *(const uint4*)sp;
                v1 = *(const uint4*)(sp + 8);
            }
            *(uint4*)(As + r * 32 + kk) = v0;
            *(uint4*)(As + r * 32 + kk + 8) = v1;
        }
        {
            int kk = tid >> 3;
            int n = (tid & 7) * 16;
            const ushort_t* sp = Bm + (size_t)(k0 + kk) * N + col0 + n;
            ushort_t tmp[16];
            if (col0 + n + 16 <= N) {
                *(uint4*)tmp = *(const uint4*)sp;
                *(uint4*)(tmp + 8) = *(const uint4*)(sp + 8);
            } else {
#pragma unroll
                for (int j = 0; j < 16; ++j) {
                    int c = col0 + n + j;
                    tmp[j] = (c < N) ? sp[j] : (ushort_t)0;
                }
            }
#pragma unroll
            for (int j = 0; j < 16; ++j) Bs[(n + j) * 32 + kk] = tmp[j];
        }
        __syncthreads();
        s16x8 af[4], bfr[4];
#pragma unroll
        for (int i = 0; i < 4; ++i)
            af[i] = *(const s16x8*)(As + (wm * 64 + i * 16 + lr) * 32 + lk);
#pragma unroll
        for (int j = 0; j < 4; ++j)
            bfr[j] = *(const s16x8*)(Bs + (wn * 64 + j * 16 + lr) * 32 + lk);
#pragma unroll
        for (int i = 0; i < 4; ++i)
#pragma unroll
            for (int j = 0; j < 4; ++j)
                acc[i][j] = __builtin_amdgcn_mfma_f32_16x16x32_bf16(af[i], bfr[j], acc[i][j], 0, 0, 0);
        __syncthreads();
    }

    const int lrow = (lane >> 4) * 4;
#pragma unroll
    for (int i = 0; i < 4; ++i) {
#pragma unroll
        for (int j = 0; j < 4; ++j) {
            int gr0 = row0 + wm * 64 + i * 16 + lrow;
            int gc = col0 + wn * 64 + j * 16 + lr;
#pragma unroll
            for (int r = 0; r < 4; ++r) {
                int gr = gr0 + r;
                if (gr < M && gc < N) {
                    float v = acc[i][j][r] + bias[gc];
                    if (MODE == 0) {
                        outb[(size_t)gr * N + gc] = f2bf(v);
                    } else {
                        int t = gr >> 5, b = gr & 31;
                        outf[((size_t)(b * TT + t)) * VV + gc] = v;
                    }
                }
            }
        }
    }
}

// ---------------- persistent recurrent kernel ----------------
// 512 blocks (2/CU). Decode: q = bid&7 (XCD heuristic), r = bid>>3;
//   pcg = 2q + (r&1);  bA = r>>1.  Group = 16 blocks sharing bA.
// TWO flag barriers/step:
//   AB1: local a-slice (LDS weights) + j-sliced partial scores -> scp
//   B2 : sum 16 score slices (redundant per block), exp, S local,
//        ctx partials -> ctxP
//   C  : sum ctx partials, gate GEMV, LSTM
// bar layout: flags[bA][slot] at bar + bA*512 + slot*32

__device__ __forceinline__ void gbar16(int* flags, int myslot, int target) {
    asm volatile("s_waitcnt vmcnt(0)" ::: "memory");   // drain data stores to LLC
    __syncthreads();
    if (threadIdx.x == 0) astore_i(flags + myslot * 32, target);
    if (threadIdx.x < 16) {
        while (aload_i(flags + (int)threadIdx.x * 32) < target)
            __builtin_amdgcn_s_sleep(1);
    }
    __syncthreads();
}

__global__ __launch_bounds__(256) void k_steps(
    const ushort_t* __restrict__ fp, const ushort_t* __restrict__ fb,
    const ushort_t* __restrict__ WdecT, const float* __restrict__ bdec,
    const float* __restrict__ vatt, const float* __restrict__ bfull,
    const ushort_t* __restrict__ Wg2, const ushort_t* __restrict__ gemb,
    float* __restrict__ hbuf, const float* __restrict__ cbuf,
    float* __restrict__ scp, float* __restrict__ ctxP,
    ushort_t* __restrict__ Hb, int* __restrict__ bar) {

    __shared__ __align__(16) float hs[8 * 68];          // h padded [kh][68]
    __shared__ __align__(16) float cs[512];
    __shared__ __align__(16) float pctx[4 * 520];
    __shared__ __align__(16) ushort_t fpJ[196 * 36];    // fp j-slice, row stride 36
    __shared__ __align__(16) ushort_t wdL[8 * 256 * 8]; // Wdec slice, lane-contiguous
    __shared__ float aL[32];
    __shared__ float vsJ[32];
    __shared__ float ep[200];
    __shared__ float sS[1];

    const int bid = blockIdx.x, tid = threadIdx.x;
    const float bfull_r = bfull[0];

    const int q = bid & 7, r = bid >> 3;
    const int pcg = 2 * q + (r & 1);
    const int bA = r >> 1;
    int* flags = bar + bA * 512;

    // a-GEMV ids: aj = tid>>3 (32 j's), akh = tid&7 (64 k each)
    const int aj = tid >> 3, akh = tid & 7;
    const int j_abs = pcg * 32 + aj;
    const float bdec_r = bdec[j_abs];
    // ctx-partial ids
    const int cnt_b = (pcg < 4) ? 13 : 12;
    const int p0 = (pcg < 4) ? pcg * 13 : 52 + (pcg - 4) * 12;
    const int ps = tid >> 6, cg = tid & 63;
    // phase C ids: R = tid>>1 (d_local*4+gate), ckh = tid&1 (K half)
    const int R = tid >> 1, ckh = tid & 1;
    const int cd = pcg * 32 + (R >> 2);
    const int crow = (R & 3) * DEC + cd;
    const ushort_t* wgp = Wg2 + ((size_t)(pcg * 2 + ckh) * 64) * 1024 + R * 8;

    float creg = ((tid & 7) == 0) ? cbuf[bA * DEC + cd] : 0.f;

    // ---------- prologue: stage step-invariant data into LDS ----------
    if (tid < 32) vsJ[tid] = vatt[pcg * 32 + tid];
    // fpJ[p][jj] = fp[bA*PP+p][pcg*32+jj], uint2 chunks (4 ushorts)
    for (int i = tid; i < 196 * 8; i += 256) {
        int p = i >> 3, c = i & 7;
        uint2 v = *(const uint2*)(fp + ((size_t)bA * PP + p) * ATTD + pcg * 32 + c * 4);
        *(uint2*)(fpJ + p * 36 + c * 4) = v;
    }
    {
        const ushort_t* wp = WdecT + (size_t)j_abs * 512 + akh * 64;
#pragma unroll
        for (int c = 0; c < 8; ++c)
            *(uint4*)(wdL + ((size_t)c * 256 + tid) * 8) = *(const uint4*)(wp + c * 8);
    }
    __syncthreads();

    for (int st = 0; st < TT; ++st) {
        const float* h_in = hbuf + (size_t)(st & 1) * BB * DEC;
        float* h_out = hbuf + (size_t)((st + 1) & 1) * BB * DEC;
        const size_t trow = (size_t)st * BB + bA;
        const float gembv = bf2f(gemb[trow * (4 * DEC) + crow]);

        // ---------- phase AB1: local a-slice + j-sliced partial scores ----------
        {
            float2 hv = aload2(h_in + bA * DEC + 2 * tid);
            int k0 = 2 * tid;
            float* hrow = hs + (k0 >> 6) * 68 + (k0 & 63);
            hrow[0] = hv.x;
            hrow[1] = hv.y;
        }
        __syncthreads();
        {
            const float* hp = hs + akh * 68;
            float acc = 0.f;
#pragma unroll
            for (int c = 0; c < 8; ++c) {
                uint4 wv = *(const uint4*)(wdL + (c * 256 + tid) * 8);
                f32x4 x0 = *(const f32x4*)(hp + c * 8);
                f32x4 x1 = *(const f32x4*)(hp + c * 8 + 4);
                acc += bflo(wv.x) * x0[0] + bfhi(wv.x) * x0[1]
                     + bflo(wv.y) * x0[2] + bfhi(wv.y) * x0[3]
                     + bflo(wv.z) * x1[0] + bfhi(wv.z) * x1[1]
                     + bflo(wv.w) * x1[2] + bfhi(wv.w) * x1[3];
            }
            acc += __shfl_xor(acc, 1);
            acc += __shfl_xor(acc, 2);
            acc += __shfl_xor(acc, 4);
            if (akh == 0) aL[aj] = acc + bdec_r;
        }
        __syncthreads();
        // partial scores: thread t < 196 -> p = t, sum over this block's 32 j's
        if (tid < PP) {
            const ushort_t* fr = fpJ + tid * 36;
            float acc = 0.f;
#pragma unroll
            for (int c = 0; c < 16; ++c) {
                uint_t fv = *(const uint_t*)(fr + c * 2);
                int jj = c * 2;
                acc += ftanh(bflo(fv) + aL[jj]) * vsJ[jj];
                acc += ftanh(bfhi(fv) + aL[jj + 1]) * vsJ[jj + 1];
            }
            astore1(scp + ((size_t)bA * 16 + pcg) * 208 + tid, acc);
        }
        gbar16(flags, pcg, 2 * st + 1);

        // ---------- phase B2: sum score slices, exp, local S, ctx partials ----------
        if (tid < PP) {
            const float* sp0 = scp + (size_t)bA * 16 * 208 + tid;
            float sv = 0.f;
#pragma unroll
            for (int s = 0; s < 16; ++s) sv += aload1(sp0 + s * 208);
            ep[tid] = __expf(sv + bfull_r);
        }
        __syncthreads();
        if (tid < 64) {
            float v = ep[tid] + ep[tid + 64] + ep[tid + 128]
                    + ((tid + 192 < PP) ? ep[tid + 192] : 0.f);
            v += __shfl_xor(v, 32);
            v += __shfl_xor(v, 16);
            v += __shfl_xor(v, 8);
            v += __shfl_xor(v, 4);
            v += __shfl_xor(v, 2);
            v += __shfl_xor(v, 1);
            if (tid == 0) sS[0] = v;
        }
        {
            float a8[8];
#pragma unroll
            for (int i2 = 0; i2 < 8; ++i2) a8[i2] = 0.f;
            for (int p2 = ps; p2 < cnt_b; p2 += 4) {
                float e2 = ep[p0 + p2];
                uint4 fv = *(const uint4*)(fb + ((size_t)bA * PP + p0 + p2) * ENC + cg * 8);
                a8[0] += e2 * bflo(fv.x); a8[1] += e2 * bfhi(fv.x);
                a8[2] += e2 * bflo(fv.y); a8[3] += e2 * bfhi(fv.y);
                a8[4] += e2 * bflo(fv.z); a8[5] += e2 * bfhi(fv.z);
                a8[6] += e2 * bflo(fv.w); a8[7] += e2 * bfhi(fv.w);
            }
            float* pp = pctx + ps * 520 + cg * 8;
            *(f32x4*)pp = (f32x4){a8[0], a8[1], a8[2], a8[3]};
            *(f32x4*)(pp + 4) = (f32x4){a8[4], a8[5], a8[6], a8[7]};
        }
        __syncthreads();
        {
            int c0i = 2 * tid, c1i = 2 * tid + 1;
            float s0 = pctx[c0i] + pctx[520 + c0i] + pctx[1040 + c0i] + pctx[1560 + c0i];
            float s1 = pctx[c1i] + pctx[520 + c1i] + pctx[1040 + c1i] + pctx[1560 + c1i];
            float* cp = ctxP + ((size_t)bA * 16 + pcg) * 512;
            astore1(cp + c0i, s0);
            astore1(cp + c1i, s1);
        }
        gbar16(flags, pcg, 2 * st + 2);

        // ---------- phase C: sum ctx partials, gate GEMV (LDS x, L2 W), LSTM ----------
        {
            const float invS = __builtin_amdgcn_rcpf(sS[0]);
            float s0 = 0.f, s1 = 0.f;
            const float* cp = ctxP + (size_t)bA * 16 * 512 + 2 * tid;
#pragma unroll
            for (int sl = 0; sl < 16; ++sl) {
                float2 v = aload2(cp + sl * 512);
                s0 += v.x;
                s1 += v.y;
            }
            cs[2 * tid] = s0 * invS;
            cs[2 * tid + 1] = s1 * invS;
        }
        __syncthreads();
        {
            float acc0 = 0.f, acc1 = 0.f;
#pragma unroll 8
            for (int kc = 0; kc < 64; ++kc) {
                uint4 wv = *(const uint4*)(wgp + kc * 1024);
                const float* xp = ckh ? (hs + (kc >> 3) * 68 + (kc & 7) * 8) : (cs + kc * 8);
                f32x4 x0 = *(const f32x4*)xp;
                f32x4 x1 = *(const f32x4*)(xp + 4);
                acc0 += bflo(wv.x) * x0[0] + bfhi(wv.x) * x0[1]
                      + bflo(wv.y) * x0[2] + bfhi(wv.y) * x0[3];
                acc1 += bflo(wv.z) * x1[0] + bfhi(wv.z) * x1[1]
                      + bflo(wv.w) * x1[2] + bfhi(wv.w) * x1[3];
            }
            float acc = acc0 + acc1;
            acc += __shfl_xor(acc, 1);       // combine K halves
            acc += gembv;
            float pf = __shfl_xor(acc, 2);
            float pg = __shfl_xor(acc, 4);
            float po = __shfl_xor(acc, 6);
            if ((tid & 7) == 0) {
                float cn = fsig(pf) * creg + fsig(acc) * ftanh(pg);
                float hn = fsig(po) * ftanh(cn);
                creg = cn;
                astore1(h_out + bA * DEC + cd, hn);
                Hb[trow * DEC + cd] = f2bf(hn);
            }
        }
        gbar16(flags, pcg, 2 * st + 2 + (st < TT - 1 ? 1 : 0) - (st < TT - 1 ? 0 : 0));
        // NOTE: targets must be monotonic and unique per barrier; use 2*st+3 via next iter's
        // first barrier being 2*(st+1)+1 = 2*st+3 — but h_out must be visible before
        // next AB1 reads it, so we need this third sync point only for h.
    }
}

// ---------------- launch ----------------

extern "C" void kernel_launch(void* const* d_in, const int* in_sizes, int n_in,
                              void* d_out, int out_size, void* d_ws, size_t ws_size,
                              hipStream_t stream) {
    const float* features  = (const float*)d_in[0];
    const int*   captions  = (const int*)d_in[1];
    const float* emb       = (const float*)d_in[2];
    const float* W_enc_att = (const float*)d_in[3];
    const float* b_enc_att = (const float*)d_in[4];
    const float* W_dec_att = (const float*)d_in[5];
    const float* b_dec_att = (const float*)d_in[6];
    const float* v_att     = (const float*)d_in[7];
    const float* b_full    = (const float*)d_in[8];
    const float* W_init_h  = (const float*)d_in[9];
    const float* b_init_h  = (const float*)d_in[10];
    const float* W_init_c  = (const float*)d_in[11];
    const float* b_init_c  = (const float*)d_in[12];
    const float* W_ih      = (const float*)d_in[13];
    const float* W_hh      = (const float*)d_in[14];
    const float* b_ih      = (const float*)d_in[15];
    const float* b_hh      = (const float*)d_in[16];
    const float* W_fcn     = (const float*)d_in[17];
    const float* b_fcn     = (const float*)d_in[18];
    float* out = (float*)d_out;
    char* ws = (char*)d_ws;

    size_t o = 0;
    ushort_t* Wfcn_b  = (ushort_t*)(ws + o); o += (size_t)DEC * VV * 2;
    ushort_t* Wenc_b  = (ushort_t*)(ws + o); o += (size_t)ENC * ATTD * 2;
    ushort_t* WdecT   = (ushort_t*)(ws + o); o += (size_t)DEC * ATTD * 2;
    ushort_t* fb      = (ushort_t*)(ws + o); o += (size_t)BB * PP * ENC * 2;
    ushort_t* fp_b    = (ushort_t*)(ws + o); o += (size_t)BB * PP * ATTD * 2;
    ushort_t* emb_bf  = (ushort_t*)(ws + o); o += (size_t)TT * BB * EE * 2;
    ushort_t* WihT    = (ushort_t*)(ws + o); o += (size_t)EE * 4 * DEC * 2;
    ushort_t* gembuf  = (ushort_t*)(ws + o); o += (size_t)TT * BB * 4 * DEC * 2;
    ushort_t* Wg2     = (ushort_t*)(ws + o); o += (size_t)4 * DEC * 1024 * 2;  // 4 MB
    float*    bsum    = (float*)(ws + o);    o += (size_t)4 * DEC * 4;
    ushort_t* Hb      = (ushort_t*)(ws + o); o += (size_t)TT * BB * DEC * 2;
    float*    hbuf    = (float*)(ws + o);    o += (size_t)2 * BB * DEC * 4;
    float*    cbuf    = (float*)(ws + o);    o += (size_t)BB * DEC * 4;
    float*    scp     = (float*)(ws + o);    o += (size_t)BB * 16 * 208 * 4;   // 426 KB
    float*    ctxP    = (float*)(ws + o);    o += (size_t)BB * 16 * 512 * 4;   // 1 MB
    int*      bar     = (int*)(ws + o);      o += 16384 * 4;   // 64 KB flag barriers

    // prep
    k_cvt<<<2048, 256, 0, stream>>>(W_fcn, Wfcn_b, DEC * VV);
    k_cvt<<<256, 256, 0, stream>>>(W_enc_att, Wenc_b, ENC * ATTD);
    k_cvtD<<<256, 256, 0, stream>>>(W_dec_att, WdecT);
    k_cvt<<<2048, 256, 0, stream>>>(features, fb, BB * PP * ENC);
    k_embed_bf<<<1024, 256, 0, stream>>>(captions, emb, emb_bf);
    k_cvtT<<<1024, 256, 0, stream>>>(W_ih, WihT);
    k_cvtG2<<<4096, 256, 0, stream>>>(W_ih, W_hh, Wg2);
    k_bsum<<<8, 256, 0, stream>>>(b_ih, b_hh, bsum, 4 * DEC);
    k_init<<<32, 256, 0, stream>>>(features, W_init_h, b_init_h, W_init_c, b_init_c,
                                   hbuf, cbuf, bar);
    // feat_proj = features @ W_enc_att + b_enc_att (bf16)
    k_gemm<0><<<dim3((BB * PP) / 128, ATTD / 128), 256, 0, stream>>>(
        fb, Wenc_b, b_enc_att, fp_b, nullptr, BB * PP, ATTD, ENC);
    // gates_emb = embeds @ W_ih[:, :256]^T + (b_ih + b_hh)  (bf16)
    k_gemm<0><<<dim3((TT * BB + 127) / 128, (4 * DEC) / 128), 256, 0, stream>>>(
        emb_bf, WihT, bsum, gembuf, nullptr, TT * BB, 4 * DEC, EE);

    // persistent recurrent kernel
    k_steps<<<NBLK, 256, 0, stream>>>(fp_b, fb, WdecT, b_dec_att, v_att, b_full,
                                      Wg2, gembuf, hbuf, cbuf,
                                      scp, ctxP, Hb, bar);

    // out = H @ W_fcn + b_fcn, scattered to [b][t][v]
    k_gemm<1><<<dim3((TT * BB + 127) / 128, (VV + 127) / 128), 256, 0, stream>>>(
        Hb, Wfcn_b, b_fcn, nullptr, out, TT * BB, VV, DEC);
}